// Round 1
// baseline (3571.655 us; speedup 1.0000x reference)
//
#include <hip/hip_runtime.h>

// MultiHopGCN: x[N,128] f32, edge_index[2,E] i32, W1[128,64], b1[64], hw1[2],
//              W2[64,64], b2[64], hw2[2] -> out[N,64] f32
// out = conv2(relu(conv1(x)))  where conv = lin + 2 hops of normalized add-agg.

#define TPB 256

__global__ void k_init_deg(float* __restrict__ deg, int n) {
    int i = blockIdx.x * blockDim.x + threadIdx.x;
    if (i < n) deg[i] = 1.0f;  // self-loop
}

__global__ void k_deg_atomic(const int* __restrict__ row, float* __restrict__ deg, int E) {
    int i = blockIdx.x * blockDim.x + threadIdx.x;
    if (i < E) unsafeAtomicAdd(&deg[row[i]], 1.0f);
}

__global__ void k_rsqrt(float* __restrict__ d, int n) {
    int i = blockIdx.x * blockDim.x + threadIdx.x;
    if (i < n) d[i] = rsqrtf(d[i]);
}

// out[n,:] = dis[n]^2 * h[n,:]   (self-loop contribution == init of aggregation)
__global__ void k_self_init(const float4* __restrict__ h, float4* __restrict__ out,
                            const float* __restrict__ dis, int cnt /* = n*16 */) {
    int i = blockIdx.x * blockDim.x + threadIdx.x;
    if (i >= cnt) return;
    int node = i >> 4;
    float s = dis[node];
    s *= s;
    float4 v = h[i];
    out[i] = make_float4(v.x * s, v.y * s, v.z * s, v.w * s);
}

// edge-parallel scatter: 16 threads per edge, each thread 4 channels (float4)
__global__ void k_spmm_atomic(const float* __restrict__ h, float* __restrict__ out,
                              const int* __restrict__ row, const int* __restrict__ col,
                              const float* __restrict__ dis, int E) {
    int gid = blockIdx.x * blockDim.x + threadIdx.x;
    int e = gid >> 4;
    if (e >= E) return;
    int l = gid & 15;
    int r = row[e], c = col[e];
    float nrm = dis[r] * dis[c];
    const float4 v = *(const float4*)(h + (size_t)r * 64 + l * 4);
    float* o = out + (size_t)c * 64 + l * 4;
    unsafeAtomicAdd(o + 0, nrm * v.x);
    unsafeAtomicAdd(o + 1, nrm * v.y);
    unsafeAtomicAdd(o + 2, nrm * v.z);
    unsafeAtomicAdd(o + 3, nrm * v.w);
}

// out[N,64] = x[N,K] @ W[K,64] + b   (block: 16 rows x 16 threads x 4 cols)
template <int K>
__global__ void k_lin(const float* __restrict__ x, const float* __restrict__ W,
                      const float* __restrict__ b, float* __restrict__ out, int n) {
    __shared__ float Ws[K][64];
    __shared__ float xs[16][K + 4];  // +4 pad: keeps float4 alignment, spreads banks
    int tid = threadIdx.x;
    for (int i = tid; i < K * 64 / 4; i += TPB)
        ((float4*)&Ws[0][0])[i] = ((const float4*)W)[i];
    int row0 = blockIdx.x * 16;
    for (int i = tid; i < 16 * (K / 4); i += TPB) {
        int r = i / (K / 4), k4 = i % (K / 4);
        int gr = row0 + r;
        float4 v = (gr < n) ? ((const float4*)(x + (size_t)gr * K))[k4]
                            : make_float4(0.f, 0.f, 0.f, 0.f);
        ((float4*)&xs[r][0])[k4] = v;
    }
    __syncthreads();
    int r = tid >> 4, c4 = (tid & 15) * 4;
    float4 acc = make_float4(b[c4], b[c4 + 1], b[c4 + 2], b[c4 + 3]);
#pragma unroll 8
    for (int k = 0; k < K; ++k) {
        float xv = xs[r][k];
        float4 w = *(const float4*)&Ws[k][c4];
        acc.x += xv * w.x;
        acc.y += xv * w.y;
        acc.z += xv * w.z;
        acc.w += xv * w.w;
    }
    int gr = row0 + r;
    if (gr < n) *(float4*)(out + (size_t)gr * 64 + c4) = acc;
}

// o = hw[0]*a + hw[1]*b  (optionally relu'd)
__global__ void k_combine(const float4* __restrict__ a, const float4* __restrict__ b,
                          float4* __restrict__ o, const float* __restrict__ hw,
                          int cnt, int relu) {
    int i = blockIdx.x * blockDim.x + threadIdx.x;
    if (i >= cnt) return;
    float w0 = hw[0], w1 = hw[1];
    float4 xa = a[i], xb = b[i];
    float4 rv;
    rv.x = w0 * xa.x + w1 * xb.x;
    rv.y = w0 * xa.y + w1 * xb.y;
    rv.z = w0 * xa.z + w1 * xb.z;
    rv.w = w0 * xa.w + w1 * xb.w;
    if (relu) {
        rv.x = fmaxf(rv.x, 0.f);
        rv.y = fmaxf(rv.y, 0.f);
        rv.z = fmaxf(rv.z, 0.f);
        rv.w = fmaxf(rv.w, 0.f);
    }
    o[i] = rv;
}

extern "C" void kernel_launch(void* const* d_in, const int* in_sizes, int n_in,
                              void* d_out, int out_size, void* d_ws, size_t ws_size,
                              hipStream_t stream) {
    const float* x   = (const float*)d_in[0];
    const int*   ei  = (const int*)d_in[1];
    const float* W1  = (const float*)d_in[2];
    const float* b1  = (const float*)d_in[3];
    const float* hw1 = (const float*)d_in[4];
    const float* W2  = (const float*)d_in[5];
    const float* b2  = (const float*)d_in[6];
    const float* hw2 = (const float*)d_in[7];
    float* out = (float*)d_out;

    const int E = in_sizes[1] / 2;
    const int n = out_size / 64;
    const int* row = ei;
    const int* col = ei + E;

    char* ws = (char*)d_ws;
    float* dis = (float*)ws;                       // n floats (deg -> dis in place)
    size_t bufBytes = (size_t)n * 64 * sizeof(float);
    float* A = (float*)(ws + (1 << 20));
    float* B = (float*)(ws + (1 << 20) + bufBytes);
    float* C = out;  // d_out doubles as scratch

    const int cnt4 = n * 16;                        // float4 elements per [n,64] buffer
    dim3 blk(TPB);
    dim3 gN((n + TPB - 1) / TPB);
    dim3 gE((E + TPB - 1) / TPB);
    dim3 g4((cnt4 + TPB - 1) / TPB);
    dim3 gS(((size_t)E * 16 + TPB - 1) / TPB);
    dim3 gLin((n + 15) / 16);

    // degree -> dis = deg^-1/2
    k_init_deg<<<gN, blk, 0, stream>>>(dis, n);
    k_deg_atomic<<<gE, blk, 0, stream>>>(row, dis, E);
    k_rsqrt<<<gN, blk, 0, stream>>>(dis, n);

    // ---- layer 1 ----
    k_lin<128><<<gLin, blk, 0, stream>>>(x, W1, b1, A, n);        // A = x@W1+b1
    k_self_init<<<g4, blk, 0, stream>>>((const float4*)A, (float4*)B, dis, cnt4);
    k_spmm_atomic<<<gS, blk, 0, stream>>>(A, B, row, col, dis, E);  // B = h1
    k_self_init<<<g4, blk, 0, stream>>>((const float4*)B, (float4*)C, dis, cnt4);
    k_spmm_atomic<<<gS, blk, 0, stream>>>(B, C, row, col, dis, E);  // C = h2
    k_combine<<<g4, blk, 0, stream>>>((const float4*)B, (const float4*)C, (float4*)A,
                                      hw1, cnt4, 1);              // A = relu(out1)

    // ---- layer 2 ----
    k_lin<64><<<gLin, blk, 0, stream>>>(A, W2, b2, B, n);         // B = g0
    k_self_init<<<g4, blk, 0, stream>>>((const float4*)B, (float4*)A, dis, cnt4);
    k_spmm_atomic<<<gS, blk, 0, stream>>>(B, A, row, col, dis, E);  // A = g1
    k_self_init<<<g4, blk, 0, stream>>>((const float4*)A, (float4*)C, dis, cnt4);
    k_spmm_atomic<<<gS, blk, 0, stream>>>(A, C, row, col, dis, E);  // C(d_out) = g2
    k_combine<<<g4, blk, 0, stream>>>((const float4*)A, (const float4*)C, (float4*)out,
                                      hw2, cnt4, 0);              // out = hw2[0]*g1+hw2[1]*g2
}

// Round 3
// 645.391 us; speedup vs baseline: 5.5341x; 5.5341x over previous
//
#include <hip/hip_runtime.h>

// MultiHopGCN: x[N,128] f32, edge_index[2,E] i32, W1[128,64], b1[64], hw1[2],
//              W2[64,64], b2[64], hw2[2] -> out[N,64] f32
// Strategy: build CSC (in-edges per node) once, then each hop is a gather
// with register accumulation (no atomics on the feature matrix).

#define TPB 256

// ---- graph build ---------------------------------------------------------

// counts[col[e]]++ (aggregation targets), deg[row[e]]++ (for normalization)
__global__ void k_hist(const int* __restrict__ row, const int* __restrict__ col,
                       int* __restrict__ cnt, int* __restrict__ deg, int E) {
    int i = blockIdx.x * blockDim.x + threadIdx.x;
    if (i >= E) return;
    atomicAdd(&cnt[col[i]], 1);
    atomicAdd(&deg[row[i]], 1);
}

// dis[i] = (deg[i] + 1)^-1/2   (+1 = self loop)
__global__ void k_dis(const int* __restrict__ deg, float* __restrict__ dis, int n) {
    int i = blockIdx.x * blockDim.x + threadIdx.x;
    if (i < n) dis[i] = rsqrtf((float)deg[i] + 1.0f);
}

// single-block exclusive scan of cnt[0..n) -> off[0..n], and cur = copy of off.
// cnt may alias off. blockDim.x must be 1024.
__global__ void k_scan(const int* __restrict__ cnt, int* __restrict__ off,
                       int* __restrict__ cur, int n, int E) {
    __shared__ int sdata[1024];
    int t = threadIdx.x;
    int chunk = (n + 1023) >> 10;
    int s = t * chunk, e = min(s + chunk, n);
    int sum = 0;
    for (int i = s; i < e; ++i) sum += cnt[i];
    sdata[t] = sum;
    __syncthreads();
    for (int d = 1; d < 1024; d <<= 1) {
        int v = (t >= d) ? sdata[t - d] : 0;
        __syncthreads();
        sdata[t] += v;
        __syncthreads();
    }
    int run = sdata[t] - sum;  // exclusive prefix of this chunk
    for (int i = s; i < e; ++i) {
        int c = cnt[i];
        off[i] = run;
        cur[i] = run;
        run += c;
    }
    if (t == 1023) off[n] = E;
}

// place each edge's source row into its destination's CSC slot
__global__ void k_place(const int* __restrict__ row, const int* __restrict__ col,
                        int* __restrict__ cur, int* __restrict__ csc, int E) {
    int i = blockIdx.x * blockDim.x + threadIdx.x;
    if (i >= E) return;
    int p = atomicAdd(&cur[col[i]], 1);
    csc[p] = row[i];
}

// ---- compute -------------------------------------------------------------

// out[N,64] = x[N,K] @ W[K,64] + b   (block: 16 rows x 16 threads x 4 cols)
template <int K>
__global__ void k_lin(const float* __restrict__ x, const float* __restrict__ W,
                      const float* __restrict__ b, float* __restrict__ out, int n) {
    __shared__ float Ws[K][64];
    __shared__ float xs[16][K + 4];
    int tid = threadIdx.x;
    for (int i = tid; i < K * 64 / 4; i += TPB)
        ((float4*)&Ws[0][0])[i] = ((const float4*)W)[i];
    int row0 = blockIdx.x * 16;
    for (int i = tid; i < 16 * (K / 4); i += TPB) {
        int r = i / (K / 4), k4 = i % (K / 4);
        int gr = row0 + r;
        float4 v = (gr < n) ? ((const float4*)(x + (size_t)gr * K))[k4]
                            : make_float4(0.f, 0.f, 0.f, 0.f);
        ((float4*)&xs[r][0])[k4] = v;
    }
    __syncthreads();
    int r = tid >> 4, c4 = (tid & 15) * 4;
    float4 acc = make_float4(b[c4], b[c4 + 1], b[c4 + 2], b[c4 + 3]);
#pragma unroll 8
    for (int k = 0; k < K; ++k) {
        float xv = xs[r][k];
        float4 w = *(const float4*)&Ws[k][c4];
        acc.x += xv * w.x;
        acc.y += xv * w.y;
        acc.z += xv * w.z;
        acc.w += xv * w.w;
    }
    int gr = row0 + r;
    if (gr < n) *(float4*)(out + (size_t)gr * 64 + c4) = acc;
}

// Per-node gather aggregation. 16 lanes per node, float4 per lane.
//   agg[c] = dis[c]^2*h[c] + sum_{e in in(c)} dis[r]*dis[c]*h[r]
// mode 0: out = agg
// mode 1: out = relu(hw[0]*h + hw[1]*agg)
// mode 2: out = hw[0]*h + hw[1]*agg
__global__ void k_gather(const float* __restrict__ h, float* __restrict__ out,
                         const int* __restrict__ off, const int* __restrict__ csc,
                         const float* __restrict__ dis, const float* __restrict__ hw,
                         int n, int mode) {
    int gid = blockIdx.x * blockDim.x + threadIdx.x;
    int node = gid >> 4;
    if (node >= n) return;
    int l = gid & 15;
    const float4* h4 = (const float4*)h;
    float4* out4 = (float4*)out;
    float dc = dis[node];
    float4 hv = h4[node * 16 + l];
    float sc = dc * dc;
    float4 acc = make_float4(sc * hv.x, sc * hv.y, sc * hv.z, sc * hv.w);
    int s = off[node], e = off[node + 1];
    for (int i = s; i < e; ++i) {
        int r = csc[i];
        float nr = dis[r] * dc;
        float4 v = h4[r * 16 + l];
        acc.x += nr * v.x;
        acc.y += nr * v.y;
        acc.z += nr * v.z;
        acc.w += nr * v.w;
    }
    if (mode) {
        float w0 = hw[0], w1 = hw[1];
        acc.x = w0 * hv.x + w1 * acc.x;
        acc.y = w0 * hv.y + w1 * acc.y;
        acc.z = w0 * hv.z + w1 * acc.z;
        acc.w = w0 * hv.w + w1 * acc.w;
        if (mode == 1) {
            acc.x = fmaxf(acc.x, 0.f);
            acc.y = fmaxf(acc.y, 0.f);
            acc.z = fmaxf(acc.z, 0.f);
            acc.w = fmaxf(acc.w, 0.f);
        }
    }
    out4[node * 16 + l] = acc;
}

// ---- launch --------------------------------------------------------------

static inline size_t align_up(size_t v, size_t a) { return (v + a - 1) & ~(a - 1); }

extern "C" void kernel_launch(void* const* d_in, const int* in_sizes, int n_in,
                              void* d_out, int out_size, void* d_ws, size_t ws_size,
                              hipStream_t stream) {
    const float* x   = (const float*)d_in[0];
    const int*   ei  = (const int*)d_in[1];
    const float* W1  = (const float*)d_in[2];
    const float* b1  = (const float*)d_in[3];
    const float* hw1 = (const float*)d_in[4];
    const float* W2  = (const float*)d_in[5];
    const float* b2  = (const float*)d_in[6];
    const float* hw2 = (const float*)d_in[7];
    float* out = (float*)d_out;

    const int E = in_sizes[1] / 2;
    const int n = out_size / 64;
    const int* row = ei;
    const int* col = ei + E;

    char* ws = (char*)d_ws;
    size_t o = 0;
    float* dis = (float*)(ws + o); o = align_up(o + (size_t)n * 4, 512);
    int*   off = (int*)(ws + o);   size_t off_o = o; o = align_up(o + (size_t)(n + 1) * 4, 512);
    int*   cur = (int*)(ws + o);   size_t cur_end = o + (size_t)n * 4; o = align_up(cur_end, 512);
    int*   csc = (int*)(ws + o);   o = align_up(o + (size_t)E * 4, 512);
    float* A   = (float*)(ws + o); o += (size_t)n * 64 * 4;
    float* B   = (float*)(ws + o); o += (size_t)n * 64 * 4;
    (void)ws_size;

    const int cnt4 = n * 16;
    dim3 blk(TPB);
    dim3 gE((E + TPB - 1) / TPB);
    dim3 gN((n + TPB - 1) / TPB);
    dim3 gG((cnt4 + TPB - 1) / TPB);
    dim3 gLin((n + 15) / 16);

    // zero off[] and cur[] (contiguous region), build graph structures
    (void)hipMemsetAsync(ws + off_o, 0, cur_end - off_o, stream);
    k_hist<<<gE, blk, 0, stream>>>(row, col, off /*cnt*/, cur /*deg*/, E);
    k_dis<<<gN, blk, 0, stream>>>(cur /*deg*/, dis, n);
    k_scan<<<1, 1024, 0, stream>>>(off, off, cur, n, E);  // in-place scan + cursor copy
    k_place<<<gE, blk, 0, stream>>>(row, col, cur, csc, E);

    // ---- layer 1 ----
    k_lin<128><<<gLin, blk, 0, stream>>>(x, W1, b1, A, n);             // A = h0 = x@W1+b1
    k_gather<<<gG, blk, 0, stream>>>(A, B, off, csc, dis, hw1, n, 0);  // B = h1
    k_gather<<<gG, blk, 0, stream>>>(B, A, off, csc, dis, hw1, n, 1);  // A = relu(w0*h1+w1*h2)

    // ---- layer 2 ----
    k_lin<64><<<gLin, blk, 0, stream>>>(A, W2, b2, B, n);              // B = g0
    k_gather<<<gG, blk, 0, stream>>>(B, A, off, csc, dis, hw2, n, 0);  // A = g1
    k_gather<<<gG, blk, 0, stream>>>(A, out, off, csc, dis, hw2, n, 2);// out = w0*g1+w1*g2
}

// Round 4
// 426.545 us; speedup vs baseline: 8.3734x; 1.5131x over previous
//
#include <hip/hip_runtime.h>

// MultiHopGCN: x[N,128] f32, edge_index[2,E] i32, W1[128,64], b1[64], hw1[2],
//              W2[64,64], b2[64], hw2[2] -> out[N,64] f32
// CSC build (multi-block scan) + per-node gather aggregation.

#define TPB 256

// ---- graph build ---------------------------------------------------------

__global__ void k_hist(const int* __restrict__ row, const int* __restrict__ col,
                       int* __restrict__ cnt, int* __restrict__ deg, int E) {
    int i = blockIdx.x * blockDim.x + threadIdx.x;
    if (i >= E) return;
    atomicAdd(&cnt[col[i]], 1);
    atomicAdd(&deg[row[i]], 1);
}

// dis[i] = (deg[i] + 1)^-1/2   (+1 = self loop)
__global__ void k_dis(const int* __restrict__ deg, float* __restrict__ dis, int n) {
    int i = blockIdx.x * blockDim.x + threadIdx.x;
    if (i < n) dis[i] = rsqrtf((float)deg[i] + 1.0f);
}

// --- 3-phase exclusive scan over cnt[0..n), chunk = 1024 per block ---

// phase 1: bsum[b] = sum of cnt[b*1024 .. b*1024+1024)
__global__ void k_scan_reduce(const int* __restrict__ cnt, int* __restrict__ bsum, int n) {
    int b = blockIdx.x, t = threadIdx.x;
    int base = b * 1024 + t * 4;
    int s = 0;
#pragma unroll
    for (int j = 0; j < 4; ++j) {
        int idx = base + j;
        if (idx < n) s += cnt[idx];
    }
    for (int d = 32; d; d >>= 1) s += __shfl_down(s, d, 64);
    __shared__ int wsum[4];
    if ((t & 63) == 0) wsum[t >> 6] = s;
    __syncthreads();
    if (t == 0) bsum[b] = wsum[0] + wsum[1] + wsum[2] + wsum[3];
}

// phase 2: in-place exclusive scan of bsum[0..nb), nb <= 256, single block of 256
__global__ void k_scan_bsum(int* __restrict__ bsum, int nb) {
    __shared__ int s[256];
    int t = threadIdx.x;
    int v = (t < nb) ? bsum[t] : 0;
    s[t] = v;
    __syncthreads();
    for (int d = 1; d < 256; d <<= 1) {
        int x = (t >= d) ? s[t - d] : 0;
        __syncthreads();
        s[t] += x;
        __syncthreads();
    }
    if (t < nb) bsum[t] = s[t] - v;  // exclusive
}

// phase 3: per-chunk scan, off[i] = global exclusive prefix; cur = copy; off[n]=E
__global__ void k_scan_apply(const int* __restrict__ cnt, const int* __restrict__ bsum_ex,
                             int* __restrict__ off, int* __restrict__ cur, int n, int E) {
    __shared__ int tsum[256];
    int b = blockIdx.x, t = threadIdx.x;
    int base = b * 1024 + t * 4;
    int v[4];
    int s = 0;
#pragma unroll
    for (int j = 0; j < 4; ++j) {
        int idx = base + j;
        v[j] = (idx < n) ? cnt[idx] : 0;
        s += v[j];
    }
    tsum[t] = s;
    __syncthreads();
    for (int d = 1; d < 256; d <<= 1) {
        int x = (t >= d) ? tsum[t - d] : 0;
        __syncthreads();
        tsum[t] += x;
        __syncthreads();
    }
    int run = bsum_ex[b] + tsum[t] - s;  // exclusive prefix for this thread's 4 elems
#pragma unroll
    for (int j = 0; j < 4; ++j) {
        int idx = base + j;
        if (idx < n) {
            off[idx] = run;
            cur[idx] = run;
            run += v[j];
        }
    }
    if (b == 0 && t == 0) off[n] = E;
}

// place each edge's source row into its destination's CSC slot
__global__ void k_place(const int* __restrict__ row, const int* __restrict__ col,
                        int* __restrict__ cur, int* __restrict__ csc, int E) {
    int i = blockIdx.x * blockDim.x + threadIdx.x;
    if (i >= E) return;
    int p = atomicAdd(&cur[col[i]], 1);
    csc[p] = row[i];
}

// ---- compute -------------------------------------------------------------

// out[N,64] = x[N,K] @ W[K,64] + b   (block: 16 rows x 16 threads x 4 cols)
template <int K>
__global__ void k_lin(const float* __restrict__ x, const float* __restrict__ W,
                      const float* __restrict__ b, float* __restrict__ out, int n) {
    __shared__ float Ws[K][64];
    __shared__ float xs[16][K + 4];
    int tid = threadIdx.x;
    for (int i = tid; i < K * 64 / 4; i += TPB)
        ((float4*)&Ws[0][0])[i] = ((const float4*)W)[i];
    int row0 = blockIdx.x * 16;
    for (int i = tid; i < 16 * (K / 4); i += TPB) {
        int r = i / (K / 4), k4 = i % (K / 4);
        int gr = row0 + r;
        float4 v = (gr < n) ? ((const float4*)(x + (size_t)gr * K))[k4]
                            : make_float4(0.f, 0.f, 0.f, 0.f);
        ((float4*)&xs[r][0])[k4] = v;
    }
    __syncthreads();
    int r = tid >> 4, c4 = (tid & 15) * 4;
    float4 acc = make_float4(b[c4], b[c4 + 1], b[c4 + 2], b[c4 + 3]);
#pragma unroll 8
    for (int k = 0; k < K; ++k) {
        float xv = xs[r][k];
        float4 w = *(const float4*)&Ws[k][c4];
        acc.x += xv * w.x;
        acc.y += xv * w.y;
        acc.z += xv * w.z;
        acc.w += xv * w.w;
    }
    int gr = row0 + r;
    if (gr < n) *(float4*)(out + (size_t)gr * 64 + c4) = acc;
}

// Per-node gather aggregation. 16 lanes per node, float4 per lane.
//   agg[c] = dis[c]^2*h[c] + sum_{e in in(c)} dis[r]*dis[c]*h[r]
// mode 0: out = agg
// mode 1: out = relu(hw[0]*h + hw[1]*agg)
// mode 2: out = hw[0]*h + hw[1]*agg
__global__ void k_gather(const float* __restrict__ h, float* __restrict__ out,
                         const int* __restrict__ off, const int* __restrict__ csc,
                         const float* __restrict__ dis, const float* __restrict__ hw,
                         int n, int mode) {
    int gid = blockIdx.x * blockDim.x + threadIdx.x;
    int node = gid >> 4;
    if (node >= n) return;
    int l = gid & 15;
    const float4* h4 = (const float4*)h;
    float4* out4 = (float4*)out;
    float dc = dis[node];
    float4 hv = h4[node * 16 + l];
    float sc = dc * dc;
    float4 acc = make_float4(sc * hv.x, sc * hv.y, sc * hv.z, sc * hv.w);
    int s = off[node], e = off[node + 1];
    for (int i = s; i < e; ++i) {
        int r = csc[i];
        float nr = dis[r] * dc;
        float4 v = h4[r * 16 + l];
        acc.x += nr * v.x;
        acc.y += nr * v.y;
        acc.z += nr * v.z;
        acc.w += nr * v.w;
    }
    if (mode) {
        float w0 = hw[0], w1 = hw[1];
        acc.x = w0 * hv.x + w1 * acc.x;
        acc.y = w0 * hv.y + w1 * acc.y;
        acc.z = w0 * hv.z + w1 * acc.z;
        acc.w = w0 * hv.w + w1 * acc.w;
        if (mode == 1) {
            acc.x = fmaxf(acc.x, 0.f);
            acc.y = fmaxf(acc.y, 0.f);
            acc.z = fmaxf(acc.z, 0.f);
            acc.w = fmaxf(acc.w, 0.f);
        }
    }
    out4[node * 16 + l] = acc;
}

// ---- launch --------------------------------------------------------------

static inline size_t align_up(size_t v, size_t a) { return (v + a - 1) & ~(a - 1); }

extern "C" void kernel_launch(void* const* d_in, const int* in_sizes, int n_in,
                              void* d_out, int out_size, void* d_ws, size_t ws_size,
                              hipStream_t stream) {
    const float* x   = (const float*)d_in[0];
    const int*   ei  = (const int*)d_in[1];
    const float* W1  = (const float*)d_in[2];
    const float* b1  = (const float*)d_in[3];
    const float* hw1 = (const float*)d_in[4];
    const float* W2  = (const float*)d_in[5];
    const float* b2  = (const float*)d_in[6];
    const float* hw2 = (const float*)d_in[7];
    float* out = (float*)d_out;

    const int E = in_sizes[1] / 2;
    const int n = out_size / 64;
    const int* row = ei;
    const int* col = ei + E;

    char* ws = (char*)d_ws;
    size_t o = 0;
    float* dis  = (float*)(ws + o); o = align_up(o + (size_t)n * 4, 512);
    int*   cnt  = (int*)(ws + o);   size_t cnt_o = o; o = align_up(o + (size_t)n * 4, 512);
    int*   off  = (int*)(ws + o);   o = align_up(o + (size_t)(n + 1) * 4, 512);
    int*   cur  = (int*)(ws + o);   size_t cur_end = o + (size_t)n * 4; o = align_up(cur_end, 512);
    int*   bsum = (int*)(ws + o);   o = align_up(o + 256 * 4, 512);
    int*   csc  = (int*)(ws + o);   o = align_up(o + (size_t)E * 4, 512);
    float* A    = (float*)(ws + o); o += (size_t)n * 64 * 4;
    float* B    = (float*)(ws + o); o += (size_t)n * 64 * 4;
    (void)ws_size;

    const int cnt4 = n * 16;
    const int nb = (n + 1023) / 1024;  // scan chunks (must be <= 256)
    dim3 blk(TPB);
    dim3 gE((E + TPB - 1) / TPB);
    dim3 gN((n + TPB - 1) / TPB);
    dim3 gG((cnt4 + TPB - 1) / TPB);
    dim3 gLin((n + 15) / 16);

    // zero cnt + deg(cur region reused as deg), build graph structures
    (void)hipMemsetAsync(ws + cnt_o, 0, cur_end - cnt_o, stream);
    k_hist<<<gE, blk, 0, stream>>>(row, col, cnt, cur /*deg*/, E);
    k_dis<<<gN, blk, 0, stream>>>(cur /*deg*/, dis, n);
    k_scan_reduce<<<nb, blk, 0, stream>>>(cnt, bsum, n);
    k_scan_bsum<<<1, blk, 0, stream>>>(bsum, nb);
    k_scan_apply<<<nb, blk, 0, stream>>>(cnt, bsum, off, cur, n, E);
    k_place<<<gE, blk, 0, stream>>>(row, col, cur, csc, E);

    // ---- layer 1 ----
    k_lin<128><<<gLin, blk, 0, stream>>>(x, W1, b1, A, n);             // A = h0 = x@W1+b1
    k_gather<<<gG, blk, 0, stream>>>(A, B, off, csc, dis, hw1, n, 0);  // B = h1
    k_gather<<<gG, blk, 0, stream>>>(B, A, off, csc, dis, hw1, n, 1);  // A = relu(w0*h1+w1*h2)

    // ---- layer 2 ----
    k_lin<64><<<gLin, blk, 0, stream>>>(A, W2, b2, B, n);              // B = g0
    k_gather<<<gG, blk, 0, stream>>>(B, A, off, csc, dis, hw2, n, 0);  // A = g1
    k_gather<<<gG, blk, 0, stream>>>(A, out, off, csc, dis, hw2, n, 2);// out = w0*g1+w1*g2
}

// Round 5
// 418.175 us; speedup vs baseline: 8.5410x; 1.0200x over previous
//
#include <hip/hip_runtime.h>

// MultiHopGCN: x[N,128] f32, edge_index[2,E] i32, W1[128,64], b1[64], hw1[2],
//              W2[64,64], b2[64], hw2[2] -> out[N,64] f32
// CSC build (multi-block scan) + per-node gather with precomputed edge weights.

#define TPB 256

// ---- graph build ---------------------------------------------------------

__global__ void k_hist(const int* __restrict__ row, const int* __restrict__ col,
                       int* __restrict__ cnt, int* __restrict__ deg, int E) {
    int i = blockIdx.x * blockDim.x + threadIdx.x;
    if (i >= E) return;
    atomicAdd(&cnt[col[i]], 1);
    atomicAdd(&deg[row[i]], 1);
}

// dis[i] = (deg[i] + 1)^-1/2   (+1 = self loop)
__global__ void k_dis(const int* __restrict__ deg, float* __restrict__ dis, int n) {
    int i = blockIdx.x * blockDim.x + threadIdx.x;
    if (i < n) dis[i] = rsqrtf((float)deg[i] + 1.0f);
}

// --- 3-phase exclusive scan over cnt[0..n), chunk = 1024 per block ---

__global__ void k_scan_reduce(const int* __restrict__ cnt, int* __restrict__ bsum, int n) {
    int b = blockIdx.x, t = threadIdx.x;
    int base = b * 1024 + t * 4;
    int s = 0;
#pragma unroll
    for (int j = 0; j < 4; ++j) {
        int idx = base + j;
        if (idx < n) s += cnt[idx];
    }
    for (int d = 32; d; d >>= 1) s += __shfl_down(s, d, 64);
    __shared__ int wsum[4];
    if ((t & 63) == 0) wsum[t >> 6] = s;
    __syncthreads();
    if (t == 0) bsum[b] = wsum[0] + wsum[1] + wsum[2] + wsum[3];
}

__global__ void k_scan_bsum(int* __restrict__ bsum, int nb) {
    __shared__ int s[256];
    int t = threadIdx.x;
    int v = (t < nb) ? bsum[t] : 0;
    s[t] = v;
    __syncthreads();
    for (int d = 1; d < 256; d <<= 1) {
        int x = (t >= d) ? s[t - d] : 0;
        __syncthreads();
        s[t] += x;
        __syncthreads();
    }
    if (t < nb) bsum[t] = s[t] - v;  // exclusive
}

// off[i] = global exclusive prefix; cur = copy; off[n] = E.
// cnt may alias off (each thread reads its elems before writing them).
__global__ void k_scan_apply(const int* __restrict__ cnt, const int* __restrict__ bsum_ex,
                             int* __restrict__ off, int* __restrict__ cur, int n, int E) {
    __shared__ int tsum[256];
    int b = blockIdx.x, t = threadIdx.x;
    int base = b * 1024 + t * 4;
    int v[4];
    int s = 0;
#pragma unroll
    for (int j = 0; j < 4; ++j) {
        int idx = base + j;
        v[j] = (idx < n) ? cnt[idx] : 0;
        s += v[j];
    }
    tsum[t] = s;
    __syncthreads();
    for (int d = 1; d < 256; d <<= 1) {
        int x = (t >= d) ? tsum[t - d] : 0;
        __syncthreads();
        tsum[t] += x;
        __syncthreads();
    }
    int run = bsum_ex[b] + tsum[t] - s;
#pragma unroll
    for (int j = 0; j < 4; ++j) {
        int idx = base + j;
        if (idx < n) {
            off[idx] = run;
            cur[idx] = run;
            run += v[j];
        }
    }
    if (b == 0 && t == 0) off[n] = E;
}

// place each edge into its destination's CSC slot: pair = {src row, dis[src]}
__global__ void k_place(const int* __restrict__ row, const int* __restrict__ col,
                        int* __restrict__ cur, int2* __restrict__ pair,
                        const float* __restrict__ dis, int E) {
    int i = blockIdx.x * blockDim.x + threadIdx.x;
    if (i >= E) return;
    int r = row[i];
    int p = atomicAdd(&cur[col[i]], 1);
    pair[p] = make_int2(r, __float_as_int(dis[r]));
}

// ---- compute -------------------------------------------------------------

// out[N,64] = x[N,K] @ W[K,64] + b   (block: 16 rows x 16 threads x 4 cols)
template <int K>
__global__ void k_lin(const float* __restrict__ x, const float* __restrict__ W,
                      const float* __restrict__ b, float* __restrict__ out, int n) {
    __shared__ float Ws[K][64];
    __shared__ float xs[16][K + 4];
    int tid = threadIdx.x;
    for (int i = tid; i < K * 64 / 4; i += TPB)
        ((float4*)&Ws[0][0])[i] = ((const float4*)W)[i];
    int row0 = blockIdx.x * 16;
    for (int i = tid; i < 16 * (K / 4); i += TPB) {
        int r = i / (K / 4), k4 = i % (K / 4);
        int gr = row0 + r;
        float4 v = (gr < n) ? ((const float4*)(x + (size_t)gr * K))[k4]
                            : make_float4(0.f, 0.f, 0.f, 0.f);
        ((float4*)&xs[r][0])[k4] = v;
    }
    __syncthreads();
    int r = tid >> 4, c4 = (tid & 15) * 4;
    float4 acc = make_float4(b[c4], b[c4 + 1], b[c4 + 2], b[c4 + 3]);
#pragma unroll 8
    for (int k = 0; k < K; ++k) {
        float xv = xs[r][k];
        float4 w = *(const float4*)&Ws[k][c4];
        acc.x += xv * w.x;
        acc.y += xv * w.y;
        acc.z += xv * w.z;
        acc.w += xv * w.w;
    }
    int gr = row0 + r;
    if (gr < n) *(float4*)(out + (size_t)gr * 64 + c4) = acc;
}

// Per-node gather aggregation. 16 lanes per node, float4 per lane.
//   agg = dc * ( dc*h[c] + sum_e w_e * h[r_e] ),  w_e = dis[r_e] (precomputed)
// mode 0: out = agg
// mode 1: out = relu(hw[0]*h + hw[1]*agg)
// mode 2: out = hw[0]*h + hw[1]*agg
__global__ void k_gather(const float* __restrict__ h, float* __restrict__ out,
                         const int* __restrict__ off, const int2* __restrict__ pair,
                         const float* __restrict__ dis, const float* __restrict__ hw,
                         int n, int mode) {
    int gid = blockIdx.x * blockDim.x + threadIdx.x;
    int node = gid >> 4;
    if (node >= n) return;
    int l = gid & 15;
    const float4* h4 = (const float4*)h;
    float4* out4 = (float4*)out;
    float dc = dis[node];
    float4 hv = h4[node * 16 + l];
    // S accumulates dc*hv + sum(w*h[r]); final agg = dc*S
    float4 S = make_float4(dc * hv.x, dc * hv.y, dc * hv.z, dc * hv.w);
    int s = off[node], e = off[node + 1];
    for (int i = s; i < e; i += 4) {
#pragma unroll
        for (int j = 0; j < 4; ++j) {
            int idx = i + j;
            bool ok = idx < e;
            int2 p = pair[ok ? idx : s];
            float w = ok ? __int_as_float(p.y) : 0.0f;
            float4 v = h4[p.x * 16 + l];
            S.x += w * v.x;
            S.y += w * v.y;
            S.z += w * v.z;
            S.w += w * v.w;
        }
    }
    float4 acc = make_float4(dc * S.x, dc * S.y, dc * S.z, dc * S.w);
    if (mode) {
        float w0 = hw[0], w1 = hw[1];
        acc.x = w0 * hv.x + w1 * acc.x;
        acc.y = w0 * hv.y + w1 * acc.y;
        acc.z = w0 * hv.z + w1 * acc.z;
        acc.w = w0 * hv.w + w1 * acc.w;
        if (mode == 1) {
            acc.x = fmaxf(acc.x, 0.f);
            acc.y = fmaxf(acc.y, 0.f);
            acc.z = fmaxf(acc.z, 0.f);
            acc.w = fmaxf(acc.w, 0.f);
        }
    }
    out4[node * 16 + l] = acc;
}

// ---- launch --------------------------------------------------------------

static inline size_t align_up(size_t v, size_t a) { return (v + a - 1) & ~(a - 1); }

extern "C" void kernel_launch(void* const* d_in, const int* in_sizes, int n_in,
                              void* d_out, int out_size, void* d_ws, size_t ws_size,
                              hipStream_t stream) {
    const float* x   = (const float*)d_in[0];
    const int*   ei  = (const int*)d_in[1];
    const float* W1  = (const float*)d_in[2];
    const float* b1  = (const float*)d_in[3];
    const float* hw1 = (const float*)d_in[4];
    const float* W2  = (const float*)d_in[5];
    const float* b2  = (const float*)d_in[6];
    const float* hw2 = (const float*)d_in[7];
    float* out = (float*)d_out;

    const int E = in_sizes[1] / 2;
    const int n = out_size / 64;
    const int* row = ei;
    const int* col = ei + E;

    char* ws = (char*)d_ws;
    size_t o = 0;
    float* dis  = (float*)(ws + o); o = align_up(o + (size_t)n * 4, 512);
    int*   off  = (int*)(ws + o);   size_t off_o = o; o = align_up(o + (size_t)(n + 1) * 4, 512);
    int*   cur  = (int*)(ws + o);   size_t cur_end = o + (size_t)n * 4; o = align_up(cur_end, 512);
    int*   bsum = (int*)(ws + o);   o = align_up(o + 256 * 4, 512);
    int2*  pair = (int2*)(ws + o);  o = align_up(o + (size_t)E * 8, 512);
    float* A    = (float*)(ws + o); o += (size_t)n * 64 * 4;
    float* B    = (float*)(ws + o); o += (size_t)n * 64 * 4;
    (void)ws_size;

    const int cnt4 = n * 16;
    const int nb = (n + 1023) / 1024;  // scan chunks (<= 256)
    dim3 blk(TPB);
    dim3 gE((E + TPB - 1) / TPB);
    dim3 gN((n + TPB - 1) / TPB);
    dim3 gG((cnt4 + TPB - 1) / TPB);
    dim3 gLin((n + 15) / 16);

    // zero cnt(=off) + deg(=cur), build graph structures
    (void)hipMemsetAsync(ws + off_o, 0, cur_end - off_o, stream);
    k_hist<<<gE, blk, 0, stream>>>(row, col, off /*cnt*/, cur /*deg*/, E);
    k_dis<<<gN, blk, 0, stream>>>(cur /*deg*/, dis, n);
    k_scan_reduce<<<nb, blk, 0, stream>>>(off /*cnt*/, bsum, n);
    k_scan_bsum<<<1, blk, 0, stream>>>(bsum, nb);
    k_scan_apply<<<nb, blk, 0, stream>>>(off /*cnt*/, bsum, off, cur, n, E);
    k_place<<<gE, blk, 0, stream>>>(row, col, cur, pair, dis, E);

    // ---- layer 1 ----
    k_lin<128><<<gLin, blk, 0, stream>>>(x, W1, b1, A, n);               // A = h0
    k_gather<<<gG, blk, 0, stream>>>(A, B, off, pair, dis, hw1, n, 0);   // B = h1
    k_gather<<<gG, blk, 0, stream>>>(B, A, off, pair, dis, hw1, n, 1);   // A = relu(w0*h1+w1*h2)

    // ---- layer 2 ----
    k_lin<64><<<gLin, blk, 0, stream>>>(A, W2, b2, B, n);                // B = g0
    k_gather<<<gG, blk, 0, stream>>>(B, A, off, pair, dis, hw2, n, 0);   // A = g1
    k_gather<<<gG, blk, 0, stream>>>(A, out, off, pair, dis, hw2, n, 2); // out = w0*g1+w1*g2
}

// Round 6
// 381.753 us; speedup vs baseline: 9.3559x; 1.0954x over previous
//
#include <hip/hip_runtime.h>

// MultiHopGCN: x[N,128] f32, edge_index[2,E] i32, W1[128,64], b1[64], hw1[2],
//              W2[64,64], b2[64], hw2[2] -> out[N,64] f32
// Bucketed-CSC build (one atomic pass, no scan) + wave-per-node gather.
// Overflow (in-degree > CAP) handled by tiny atomic-scatter fallback kernels
// (empty for uniform-random input).

#define TPB 256
#define CAP 40
#define OVF_CAP 65536

// ---- graph build ---------------------------------------------------------

// one pass: out-degree count + bucketed CSC placement
__global__ void k_build(const int* __restrict__ row, const int* __restrict__ col,
                        int* __restrict__ cur, int* __restrict__ deg,
                        int* __restrict__ bucket, int2* __restrict__ ovf,
                        int* __restrict__ ovf_cnt, int E) {
    int i = blockIdx.x * blockDim.x + threadIdx.x;
    if (i >= E) return;
    int r = row[i], c = col[i];
    atomicAdd(&deg[r], 1);
    int slot = atomicAdd(&cur[c], 1);
    if (slot < CAP) {
        bucket[c * CAP + slot] = r;
    } else {
        int p = atomicAdd(ovf_cnt, 1);
        if (p < OVF_CAP) ovf[p] = make_int2(r, c);
    }
}

// dis[i] = (deg[i] + 1)^-1/2   (+1 = self loop)
__global__ void k_dis(const int* __restrict__ deg, float* __restrict__ dis, int n) {
    int i = blockIdx.x * blockDim.x + threadIdx.x;
    if (i < n) dis[i] = rsqrtf((float)deg[i] + 1.0f);
}

// ---- compute -------------------------------------------------------------

// out[N,64] = x[N,K] @ W[K,64] + b   (block: 16 rows x 16 threads x 4 cols)
template <int K>
__global__ void k_lin(const float* __restrict__ x, const float* __restrict__ W,
                      const float* __restrict__ b, float* __restrict__ out, int n) {
    __shared__ float Ws[K][64];
    __shared__ float xs[16][K + 4];
    int tid = threadIdx.x;
    for (int i = tid; i < K * 64 / 4; i += TPB)
        ((float4*)&Ws[0][0])[i] = ((const float4*)W)[i];
    int row0 = blockIdx.x * 16;
    for (int i = tid; i < 16 * (K / 4); i += TPB) {
        int r = i / (K / 4), k4 = i % (K / 4);
        int gr = row0 + r;
        float4 v = (gr < n) ? ((const float4*)(x + (size_t)gr * K))[k4]
                            : make_float4(0.f, 0.f, 0.f, 0.f);
        ((float4*)&xs[r][0])[k4] = v;
    }
    __syncthreads();
    int r = tid >> 4, c4 = (tid & 15) * 4;
    float4 acc = make_float4(b[c4], b[c4 + 1], b[c4 + 2], b[c4 + 3]);
#pragma unroll 8
    for (int k = 0; k < K; ++k) {
        float xv = xs[r][k];
        float4 w = *(const float4*)&Ws[k][c4];
        acc.x += xv * w.x;
        acc.y += xv * w.y;
        acc.z += xv * w.z;
        acc.w += xv * w.w;
    }
    int gr = row0 + r;
    if (gr < n) *(float4*)(out + (size_t)gr * 64 + c4) = acc;
}

// g0 = relu(hw[0]*hA + hw[1]*hB) @ W[64,64] + b   (combine fused into staging)
__global__ void k_lin64_relu2(const float* __restrict__ hA, const float* __restrict__ hB,
                              const float* __restrict__ W, const float* __restrict__ b,
                              const float* __restrict__ hw, float* __restrict__ out, int n) {
    __shared__ float Ws[64][64];
    __shared__ float xs[16][68];
    int tid = threadIdx.x;
    for (int i = tid; i < 64 * 64 / 4; i += TPB)
        ((float4*)&Ws[0][0])[i] = ((const float4*)W)[i];
    float w0 = hw[0], w1 = hw[1];
    int row0 = blockIdx.x * 16;
    for (int i = tid; i < 16 * 16; i += TPB) {
        int r = i >> 4, k4 = i & 15;
        int gr = row0 + r;
        float4 v = make_float4(0.f, 0.f, 0.f, 0.f);
        if (gr < n) {
            float4 a = ((const float4*)(hA + (size_t)gr * 64))[k4];
            float4 c = ((const float4*)(hB + (size_t)gr * 64))[k4];
            v.x = fmaxf(w0 * a.x + w1 * c.x, 0.f);
            v.y = fmaxf(w0 * a.y + w1 * c.y, 0.f);
            v.z = fmaxf(w0 * a.z + w1 * c.z, 0.f);
            v.w = fmaxf(w0 * a.w + w1 * c.w, 0.f);
        }
        ((float4*)&xs[r][0])[k4] = v;
    }
    __syncthreads();
    int r = tid >> 4, c4 = (tid & 15) * 4;
    float4 acc = make_float4(b[c4], b[c4 + 1], b[c4 + 2], b[c4 + 3]);
#pragma unroll 8
    for (int k = 0; k < 64; ++k) {
        float xv = xs[r][k];
        float4 w = *(const float4*)&Ws[k][c4];
        acc.x += xv * w.x;
        acc.y += xv * w.y;
        acc.z += xv * w.z;
        acc.w += xv * w.w;
    }
    int gr = row0 + r;
    if (gr < n) *(float4*)(out + (size_t)gr * 64 + c4) = acc;
}

// Wave-per-node gather: 4 edge-groups x 16 channel-lanes (float4).
//   agg = dc*(dc*h[c] + sum_e dis[r]*h[r])
// mode 0: out = agg;  mode 2: out = hw[0]*h + hw[1]*agg
__global__ void k_gather(const float* __restrict__ h, float* __restrict__ out,
                         const int* __restrict__ cur, const int* __restrict__ bucket,
                         const float* __restrict__ dis, const float* __restrict__ hw,
                         int n, int mode) {
    int node = blockIdx.x * 4 + (threadIdx.x >> 6);
    if (node >= n) return;
    int lane = threadIdx.x & 63;
    int g = lane >> 4, cl = lane & 15;
    const float4* h4 = (const float4*)h;
    float dc = dis[node];
    float4 hv = h4[node * 16 + cl];
    float4 S = (g == 0) ? make_float4(dc * hv.x, dc * hv.y, dc * hv.z, dc * hv.w)
                        : make_float4(0.f, 0.f, 0.f, 0.f);
    int deg = min(cur[node], CAP);
    const int* bp = bucket + node * CAP;
    for (int i = g; i < deg; i += 4) {
        int r = bp[i];
        float w = dis[r];
        float4 v = h4[r * 16 + cl];
        S.x += w * v.x;
        S.y += w * v.y;
        S.z += w * v.z;
        S.w += w * v.w;
    }
    // reduce the 4 edge-groups (same cl across lanes g=0..3): xor lanes 16, 32
    S.x += __shfl_xor(S.x, 16); S.y += __shfl_xor(S.y, 16);
    S.z += __shfl_xor(S.z, 16); S.w += __shfl_xor(S.w, 16);
    S.x += __shfl_xor(S.x, 32); S.y += __shfl_xor(S.y, 32);
    S.z += __shfl_xor(S.z, 32); S.w += __shfl_xor(S.w, 32);
    float4 acc = make_float4(dc * S.x, dc * S.y, dc * S.z, dc * S.w);
    if (mode == 2) {
        float w0 = hw[0], w1 = hw[1];
        acc.x = w0 * hv.x + w1 * acc.x;
        acc.y = w0 * hv.y + w1 * acc.y;
        acc.z = w0 * hv.z + w1 * acc.z;
        acc.w = w0 * hv.w + w1 * acc.w;
    }
    if (g == 0) ((float4*)out)[node * 16 + cl] = acc;
}

// overflow fallback: atomic-scatter the spilled edges (empty for random input).
// adds scale * dis[r]*dis[c]*h[r] into out[c];  scale = use_w1 ? hw[1] : 1
__global__ void k_ovf(const float* __restrict__ h, float* __restrict__ out,
                      const int2* __restrict__ ovf, const int* __restrict__ ovf_cnt,
                      const float* __restrict__ dis, const float* __restrict__ hw,
                      int use_w1) {
    int m = min(*ovf_cnt, OVF_CAP);
    if (m == 0) return;
    float scale = use_w1 ? hw[1] : 1.0f;
    int l = threadIdx.x;  // 64 threads = 64 channels
    for (int e = blockIdx.x; e < m; e += gridDim.x) {
        int2 p = ovf[e];
        float w = scale * dis[p.x] * dis[p.y];
        unsafeAtomicAdd(&out[(size_t)p.y * 64 + l], w * h[(size_t)p.x * 64 + l]);
    }
}

// ---- launch --------------------------------------------------------------

static inline size_t align_up(size_t v, size_t a) { return (v + a - 1) & ~(a - 1); }

extern "C" void kernel_launch(void* const* d_in, const int* in_sizes, int n_in,
                              void* d_out, int out_size, void* d_ws, size_t ws_size,
                              hipStream_t stream) {
    const float* x   = (const float*)d_in[0];
    const int*   ei  = (const int*)d_in[1];
    const float* W1  = (const float*)d_in[2];
    const float* b1  = (const float*)d_in[3];
    const float* hw1 = (const float*)d_in[4];
    const float* W2  = (const float*)d_in[5];
    const float* b2  = (const float*)d_in[6];
    const float* hw2 = (const float*)d_in[7];
    float* out = (float*)d_out;

    const int E = in_sizes[1] / 2;
    const int n = out_size / 64;
    const int* row = ei;
    const int* col = ei + E;

    char* ws = (char*)d_ws;
    size_t o = 0;
    float* dis    = (float*)(ws + o); o = align_up(o + (size_t)n * 4, 512);
    int*   cur    = (int*)(ws + o);   size_t z0 = o; o = align_up(o + (size_t)n * 4, 512);
    int*   deg    = (int*)(ws + o);   o = align_up(o + (size_t)n * 4, 512);
    int*   ovfcnt = (int*)(ws + o);   size_t z1 = o + 4; o = align_up(z1, 512);
    int*   bucket = (int*)(ws + o);   o = align_up(o + (size_t)n * CAP * 4, 512);
    int2*  ovf    = (int2*)(ws + o);  o = align_up(o + (size_t)OVF_CAP * 8, 512);
    float* A      = (float*)(ws + o); o += (size_t)n * 64 * 4;
    float* B      = (float*)(ws + o); o += (size_t)n * 64 * 4;
    (void)ws_size;

    dim3 blk(TPB);
    dim3 gE((E + TPB - 1) / TPB);
    dim3 gN((n + TPB - 1) / TPB);
    dim3 gG((n + 3) / 4);      // 1 wave per node, 4 waves per block
    dim3 gLin((n + 15) / 16);
    dim3 gOvf(64);

    // zero cur/deg/ovf_cnt, then one-pass build
    (void)hipMemsetAsync(ws + z0, 0, z1 - z0, stream);
    k_build<<<gE, blk, 0, stream>>>(row, col, cur, deg, bucket, ovf, ovfcnt, E);
    k_dis<<<gN, blk, 0, stream>>>(deg, dis, n);

    // ---- layer 1 ----  (combine+relu deferred into k_lin64_relu2)
    k_lin<128><<<gLin, blk, 0, stream>>>(x, W1, b1, A, n);                 // A = h0
    k_gather<<<gG, blk, 0, stream>>>(A, B, cur, bucket, dis, hw1, n, 0);   // B = h1
    k_ovf<<<gOvf, 64, 0, stream>>>(A, B, ovf, ovfcnt, dis, hw1, 0);
    k_gather<<<gG, blk, 0, stream>>>(B, out, cur, bucket, dis, hw1, n, 0); // out = h2
    k_ovf<<<gOvf, 64, 0, stream>>>(B, out, ovf, ovfcnt, dis, hw1, 0);

    // ---- layer 2 ----
    k_lin64_relu2<<<gLin, blk, 0, stream>>>(B, out, W2, b2, hw1, A, n);    // A = g0
    k_gather<<<gG, blk, 0, stream>>>(A, B, cur, bucket, dis, hw2, n, 0);   // B = g1
    k_ovf<<<gOvf, 64, 0, stream>>>(A, B, ovf, ovfcnt, dis, hw2, 0);
    k_gather<<<gG, blk, 0, stream>>>(B, out, cur, bucket, dis, hw2, n, 2); // out = w0*g1+w1*agg
    k_ovf<<<gOvf, 64, 0, stream>>>(B, out, ovf, ovfcnt, dis, hw2, 1);
}

// Round 7
// 354.458 us; speedup vs baseline: 10.0764x; 1.0770x over previous
//
#include <hip/hip_runtime.h>

// MultiHopGCN: x[N,128] f32, edge_index[2,E] i32, W1[128,64], b1[64], hw1[2],
//              W2[64,64], b2[64], hw2[2] -> out[N,64] f32
// Bucketed-CSC build (one atomic pass) + wave-per-node gather with int4
// edge-id prefetch (16 outstanding row gathers per wave).

#define TPB 256
#define CAP 40
#define OVF_CAP 65536

// ---- graph build ---------------------------------------------------------

__global__ void k_build(const int* __restrict__ row, const int* __restrict__ col,
                        int* __restrict__ cur, int* __restrict__ deg,
                        int* __restrict__ bucket, int2* __restrict__ ovf,
                        int* __restrict__ ovf_cnt, int E) {
    int i = blockIdx.x * blockDim.x + threadIdx.x;
    if (i >= E) return;
    int r = row[i], c = col[i];
    atomicAdd(&deg[r], 1);
    int slot = atomicAdd(&cur[c], 1);
    if (slot < CAP) {
        bucket[c * CAP + slot] = r;
    } else {
        int p = atomicAdd(ovf_cnt, 1);
        if (p < OVF_CAP) ovf[p] = make_int2(r, c);
    }
}

// dis[i] = (deg[i] + 1)^-1/2   (+1 = self loop)
__global__ void k_dis(const int* __restrict__ deg, float* __restrict__ dis, int n) {
    int i = blockIdx.x * blockDim.x + threadIdx.x;
    if (i < n) dis[i] = rsqrtf((float)deg[i] + 1.0f);
}

// ---- compute -------------------------------------------------------------

// out[N,64] = x[N,K] @ W[K,64] + b   (block: 16 rows x 16 threads x 4 cols)
template <int K>
__global__ void k_lin(const float* __restrict__ x, const float* __restrict__ W,
                      const float* __restrict__ b, float* __restrict__ out, int n) {
    __shared__ float Ws[K][64];
    __shared__ float xs[16][K + 4];
    int tid = threadIdx.x;
    for (int i = tid; i < K * 64 / 4; i += TPB)
        ((float4*)&Ws[0][0])[i] = ((const float4*)W)[i];
    int row0 = blockIdx.x * 16;
    for (int i = tid; i < 16 * (K / 4); i += TPB) {
        int r = i / (K / 4), k4 = i % (K / 4);
        int gr = row0 + r;
        float4 v = (gr < n) ? ((const float4*)(x + (size_t)gr * K))[k4]
                            : make_float4(0.f, 0.f, 0.f, 0.f);
        ((float4*)&xs[r][0])[k4] = v;
    }
    __syncthreads();
    int r = tid >> 4, c4 = (tid & 15) * 4;
    float4 acc = make_float4(b[c4], b[c4 + 1], b[c4 + 2], b[c4 + 3]);
#pragma unroll 8
    for (int k = 0; k < K; ++k) {
        float xv = xs[r][k];
        float4 w = *(const float4*)&Ws[k][c4];
        acc.x += xv * w.x;
        acc.y += xv * w.y;
        acc.z += xv * w.z;
        acc.w += xv * w.w;
    }
    int gr = row0 + r;
    if (gr < n) *(float4*)(out + (size_t)gr * 64 + c4) = acc;
}

// g0 = relu(hw[0]*hA + hw[1]*hB) @ W[64,64] + b   (combine fused into staging)
__global__ void k_lin64_relu2(const float* __restrict__ hA, const float* __restrict__ hB,
                              const float* __restrict__ W, const float* __restrict__ b,
                              const float* __restrict__ hw, float* __restrict__ out, int n) {
    __shared__ float Ws[64][64];
    __shared__ float xs[16][68];
    int tid = threadIdx.x;
    for (int i = tid; i < 64 * 64 / 4; i += TPB)
        ((float4*)&Ws[0][0])[i] = ((const float4*)W)[i];
    float w0 = hw[0], w1 = hw[1];
    int row0 = blockIdx.x * 16;
    for (int i = tid; i < 16 * 16; i += TPB) {
        int r = i >> 4, k4 = i & 15;
        int gr = row0 + r;
        float4 v = make_float4(0.f, 0.f, 0.f, 0.f);
        if (gr < n) {
            float4 a = ((const float4*)(hA + (size_t)gr * 64))[k4];
            float4 c = ((const float4*)(hB + (size_t)gr * 64))[k4];
            v.x = fmaxf(w0 * a.x + w1 * c.x, 0.f);
            v.y = fmaxf(w0 * a.y + w1 * c.y, 0.f);
            v.z = fmaxf(w0 * a.z + w1 * c.z, 0.f);
            v.w = fmaxf(w0 * a.w + w1 * c.w, 0.f);
        }
        ((float4*)&xs[r][0])[k4] = v;
    }
    __syncthreads();
    int r = tid >> 4, c4 = (tid & 15) * 4;
    float4 acc = make_float4(b[c4], b[c4 + 1], b[c4 + 2], b[c4 + 3]);
#pragma unroll 8
    for (int k = 0; k < 64; ++k) {
        float xv = xs[r][k];
        float4 w = *(const float4*)&Ws[k][c4];
        acc.x += xv * w.x;
        acc.y += xv * w.y;
        acc.z += xv * w.z;
        acc.w += xv * w.w;
    }
    int gr = row0 + r;
    if (gr < n) *(float4*)(out + (size_t)gr * 64 + c4) = acc;
}

// Wave-per-node gather: 4 edge-groups x 16 channel-lanes (float4).
// Group g int4-loads edge ids [4g, 4g+4) then issues 4 independent row
// gathers; pass stride 16 edges. Slots beyond deg clamp to `node`, weight 0.
//   agg = dc*(dc*h[c] + sum_e dis[r]*h[r])
// mode 0: out = agg;  mode 2: out = hw[0]*h + hw[1]*agg
__global__ void k_gather(const float* __restrict__ h, float* __restrict__ out,
                         const int* __restrict__ cur, const int* __restrict__ bucket,
                         const float* __restrict__ dis, const float* __restrict__ hw,
                         int n, int mode) {
    int node = blockIdx.x * 4 + (threadIdx.x >> 6);
    if (node >= n) return;
    int lane = threadIdx.x & 63;
    int g = lane >> 4, cl = lane & 15;
    const float4* h4 = (const float4*)h;
    float dc = dis[node];
    float4 hv = h4[node * 16 + cl];
    float4 S = (g == 0) ? make_float4(dc * hv.x, dc * hv.y, dc * hv.z, dc * hv.w)
                        : make_float4(0.f, 0.f, 0.f, 0.f);
    int deg = min(cur[node], CAP);
    const int4* bp4 = (const int4*)(bucket + node * CAP);  // node*160 B, 16B-aligned
    for (int base = g * 4; base < deg; base += 16) {
        int4 e = bp4[base >> 2];
        int r0 = (base + 0 < deg) ? e.x : node;
        int r1 = (base + 1 < deg) ? e.y : node;
        int r2 = (base + 2 < deg) ? e.z : node;
        int r3 = (base + 3 < deg) ? e.w : node;
        float w0 = (base + 0 < deg) ? dis[r0] : 0.f;
        float w1 = (base + 1 < deg) ? dis[r1] : 0.f;
        float w2 = (base + 2 < deg) ? dis[r2] : 0.f;
        float w3 = (base + 3 < deg) ? dis[r3] : 0.f;
        float4 v0 = h4[r0 * 16 + cl];
        float4 v1 = h4[r1 * 16 + cl];
        float4 v2 = h4[r2 * 16 + cl];
        float4 v3 = h4[r3 * 16 + cl];
        S.x += w0 * v0.x + w1 * v1.x + w2 * v2.x + w3 * v3.x;
        S.y += w0 * v0.y + w1 * v1.y + w2 * v2.y + w3 * v3.y;
        S.z += w0 * v0.z + w1 * v1.z + w2 * v2.z + w3 * v3.z;
        S.w += w0 * v0.w + w1 * v1.w + w2 * v2.w + w3 * v3.w;
    }
    // reduce the 4 edge-groups (same cl): xor lanes 16, 32
    S.x += __shfl_xor(S.x, 16); S.y += __shfl_xor(S.y, 16);
    S.z += __shfl_xor(S.z, 16); S.w += __shfl_xor(S.w, 16);
    S.x += __shfl_xor(S.x, 32); S.y += __shfl_xor(S.y, 32);
    S.z += __shfl_xor(S.z, 32); S.w += __shfl_xor(S.w, 32);
    float4 acc = make_float4(dc * S.x, dc * S.y, dc * S.z, dc * S.w);
    if (mode == 2) {
        float w0 = hw[0], w1 = hw[1];
        acc.x = w0 * hv.x + w1 * acc.x;
        acc.y = w0 * hv.y + w1 * acc.y;
        acc.z = w0 * hv.z + w1 * acc.z;
        acc.w = w0 * hv.w + w1 * acc.w;
    }
    if (g == 0) ((float4*)out)[node * 16 + cl] = acc;
}

// overflow fallback: atomic-scatter the spilled edges (empty for random input).
// adds scale * dis[r]*dis[c]*h[r] into out[c];  scale = use_w1 ? hw[1] : 1
__global__ void k_ovf(const float* __restrict__ h, float* __restrict__ out,
                      const int2* __restrict__ ovf, const int* __restrict__ ovf_cnt,
                      const float* __restrict__ dis, const float* __restrict__ hw,
                      int use_w1) {
    int m = min(*ovf_cnt, OVF_CAP);
    if (m == 0) return;
    float scale = use_w1 ? hw[1] : 1.0f;
    int l = threadIdx.x;  // 64 threads = 64 channels
    for (int e = blockIdx.x; e < m; e += gridDim.x) {
        int2 p = ovf[e];
        float w = scale * dis[p.x] * dis[p.y];
        unsafeAtomicAdd(&out[(size_t)p.y * 64 + l], w * h[(size_t)p.x * 64 + l]);
    }
}

// ---- launch --------------------------------------------------------------

static inline size_t align_up(size_t v, size_t a) { return (v + a - 1) & ~(a - 1); }

extern "C" void kernel_launch(void* const* d_in, const int* in_sizes, int n_in,
                              void* d_out, int out_size, void* d_ws, size_t ws_size,
                              hipStream_t stream) {
    const float* x   = (const float*)d_in[0];
    const int*   ei  = (const int*)d_in[1];
    const float* W1  = (const float*)d_in[2];
    const float* b1  = (const float*)d_in[3];
    const float* hw1 = (const float*)d_in[4];
    const float* W2  = (const float*)d_in[5];
    const float* b2  = (const float*)d_in[6];
    const float* hw2 = (const float*)d_in[7];
    float* out = (float*)d_out;

    const int E = in_sizes[1] / 2;
    const int n = out_size / 64;
    const int* row = ei;
    const int* col = ei + E;

    char* ws = (char*)d_ws;
    size_t o = 0;
    float* dis    = (float*)(ws + o); o = align_up(o + (size_t)n * 4, 512);
    int*   cur    = (int*)(ws + o);   size_t z0 = o; o = align_up(o + (size_t)n * 4, 512);
    int*   deg    = (int*)(ws + o);   o = align_up(o + (size_t)n * 4, 512);
    int*   ovfcnt = (int*)(ws + o);   size_t z1 = o + 4; o = align_up(z1, 512);
    int*   bucket = (int*)(ws + o);   o = align_up(o + (size_t)n * CAP * 4, 512);
    int2*  ovf    = (int2*)(ws + o);  o = align_up(o + (size_t)OVF_CAP * 8, 512);
    float* A      = (float*)(ws + o); o += (size_t)n * 64 * 4;
    float* B      = (float*)(ws + o); o += (size_t)n * 64 * 4;
    (void)ws_size;

    dim3 blk(TPB);
    dim3 gE((E + TPB - 1) / TPB);
    dim3 gN((n + TPB - 1) / TPB);
    dim3 gG((n + 3) / 4);      // 1 wave per node, 4 waves per block
    dim3 gLin((n + 15) / 16);
    dim3 gOvf(64);

    // zero cur/deg/ovf_cnt, then one-pass build
    (void)hipMemsetAsync(ws + z0, 0, z1 - z0, stream);
    k_build<<<gE, blk, 0, stream>>>(row, col, cur, deg, bucket, ovf, ovfcnt, E);
    k_dis<<<gN, blk, 0, stream>>>(deg, dis, n);

    // ---- layer 1 ----  (combine+relu deferred into k_lin64_relu2)
    k_lin<128><<<gLin, blk, 0, stream>>>(x, W1, b1, A, n);                 // A = h0
    k_gather<<<gG, blk, 0, stream>>>(A, B, cur, bucket, dis, hw1, n, 0);   // B = h1
    k_ovf<<<gOvf, 64, 0, stream>>>(A, B, ovf, ovfcnt, dis, hw1, 0);
    k_gather<<<gG, blk, 0, stream>>>(B, out, cur, bucket, dis, hw1, n, 0); // out = h2
    k_ovf<<<gOvf, 64, 0, stream>>>(B, out, ovf, ovfcnt, dis, hw1, 0);

    // ---- layer 2 ----
    k_lin64_relu2<<<gLin, blk, 0, stream>>>(B, out, W2, b2, hw1, A, n);    // A = g0
    k_gather<<<gG, blk, 0, stream>>>(A, B, cur, bucket, dis, hw2, n, 0);   // B = g1
    k_ovf<<<gOvf, 64, 0, stream>>>(A, B, ovf, ovfcnt, dis, hw2, 0);
    k_gather<<<gG, blk, 0, stream>>>(B, out, cur, bucket, dis, hw2, n, 2); // out = w0*g1+w1*agg
    k_ovf<<<gOvf, 64, 0, stream>>>(B, out, ovf, ovfcnt, dis, hw2, 1);
}

// Round 8
// 351.210 us; speedup vs baseline: 10.1696x; 1.0092x over previous
//
#include <hip/hip_runtime.h>

// MultiHopGCN: x[N,128] f32, edge_index[2,E] i32, W1[128,64], b1[64], hw1[2],
//              W2[64,64], b2[64], hw2[2] -> out[N,64] f32
// Bucketed-CSC build FUSED with layer-1 GEMM (independent work, one launch).
// Wave-per-node gather with int4 edge prefetch; overflow handled inline.

#define TPB 256
#define CAP 40
#define OVF_CAP 65536

// ---- fused build + lin128 -------------------------------------------------
// blocks [0, nBuild): one-pass bucketed-CSC build + degree histogram
// blocks [nBuild, nBuild+nLin): A = x @ W1 + b1  (16 rows x 16 thr x 4 cols)
__global__ void k_build_lin(const int* __restrict__ row, const int* __restrict__ col,
                            int* __restrict__ cur, int* __restrict__ deg,
                            int* __restrict__ bucket, int2* __restrict__ ovf,
                            int* __restrict__ ovf_cnt, int E, int nBuild,
                            const float* __restrict__ x, const float* __restrict__ W,
                            const float* __restrict__ b, float* __restrict__ out, int n) {
    if (blockIdx.x < nBuild) {
        int i = blockIdx.x * TPB + threadIdx.x;
        if (i >= E) return;
        int r = row[i], c = col[i];
        atomicAdd(&deg[r], 1);
        int slot = atomicAdd(&cur[c], 1);
        if (slot < CAP) {
            bucket[c * CAP + slot] = r;
        } else {
            int p = atomicAdd(ovf_cnt, 1);
            if (p < OVF_CAP) ovf[p] = make_int2(r, c);
        }
        return;
    }
    // ---- lin128 path ----
    constexpr int K = 128;
    __shared__ float Ws[K][64];
    __shared__ float xs[16][K + 4];
    int tid = threadIdx.x;
    for (int i = tid; i < K * 64 / 4; i += TPB)
        ((float4*)&Ws[0][0])[i] = ((const float4*)W)[i];
    int row0 = (blockIdx.x - nBuild) * 16;
    for (int i = tid; i < 16 * (K / 4); i += TPB) {
        int r = i / (K / 4), k4 = i % (K / 4);
        int gr = row0 + r;
        float4 v = (gr < n) ? ((const float4*)(x + (size_t)gr * K))[k4]
                            : make_float4(0.f, 0.f, 0.f, 0.f);
        ((float4*)&xs[r][0])[k4] = v;
    }
    __syncthreads();
    int r = tid >> 4, c4 = (tid & 15) * 4;
    float4 acc = make_float4(b[c4], b[c4 + 1], b[c4 + 2], b[c4 + 3]);
#pragma unroll 8
    for (int k = 0; k < K; ++k) {
        float xv = xs[r][k];
        float4 w = *(const float4*)&Ws[k][c4];
        acc.x += xv * w.x;
        acc.y += xv * w.y;
        acc.z += xv * w.z;
        acc.w += xv * w.w;
    }
    int gr = row0 + r;
    if (gr < n) *(float4*)(out + (size_t)gr * 64 + c4) = acc;
}

// dis[i] = (deg[i] + 1)^-1/2   (+1 = self loop)
__global__ void k_dis(const int* __restrict__ deg, float* __restrict__ dis, int n) {
    int i = blockIdx.x * blockDim.x + threadIdx.x;
    if (i < n) dis[i] = rsqrtf((float)deg[i] + 1.0f);
}

// g0 = relu(hw[0]*hA + hw[1]*hB) @ W[64,64] + b   (combine fused into staging)
__global__ void k_lin64_relu2(const float* __restrict__ hA, const float* __restrict__ hB,
                              const float* __restrict__ W, const float* __restrict__ b,
                              const float* __restrict__ hw, float* __restrict__ out, int n) {
    __shared__ float Ws[64][64];
    __shared__ float xs[16][68];
    int tid = threadIdx.x;
    for (int i = tid; i < 64 * 64 / 4; i += TPB)
        ((float4*)&Ws[0][0])[i] = ((const float4*)W)[i];
    float w0 = hw[0], w1 = hw[1];
    int row0 = blockIdx.x * 16;
    for (int i = tid; i < 16 * 16; i += TPB) {
        int r = i >> 4, k4 = i & 15;
        int gr = row0 + r;
        float4 v = make_float4(0.f, 0.f, 0.f, 0.f);
        if (gr < n) {
            float4 a = ((const float4*)(hA + (size_t)gr * 64))[k4];
            float4 c = ((const float4*)(hB + (size_t)gr * 64))[k4];
            v.x = fmaxf(w0 * a.x + w1 * c.x, 0.f);
            v.y = fmaxf(w0 * a.y + w1 * c.y, 0.f);
            v.z = fmaxf(w0 * a.z + w1 * c.z, 0.f);
            v.w = fmaxf(w0 * a.w + w1 * c.w, 0.f);
        }
        ((float4*)&xs[r][0])[k4] = v;
    }
    __syncthreads();
    int r = tid >> 4, c4 = (tid & 15) * 4;
    float4 acc = make_float4(b[c4], b[c4 + 1], b[c4 + 2], b[c4 + 3]);
#pragma unroll 8
    for (int k = 0; k < 64; ++k) {
        float xv = xs[r][k];
        float4 w = *(const float4*)&Ws[k][c4];
        acc.x += xv * w.x;
        acc.y += xv * w.y;
        acc.z += xv * w.z;
        acc.w += xv * w.w;
    }
    int gr = row0 + r;
    if (gr < n) *(float4*)(out + (size_t)gr * 64 + c4) = acc;
}

// Wave-per-node gather: 4 edge-groups x 16 channel-lanes (float4).
// Group g int4-loads edge ids then issues 4 independent row gathers.
// Overflow (cur > CAP) handled inline by scanning the global ovf list
// (never taken for in-cap nodes; one predicated branch).
//   agg = dc*(dc*h[c] + sum_e dis[r]*h[r])
// mode 0: out = agg;  mode 2: out = hw[0]*h + hw[1]*agg
__global__ void k_gather(const float* __restrict__ h, float* __restrict__ out,
                         const int* __restrict__ cur, const int* __restrict__ bucket,
                         const float* __restrict__ dis, const float* __restrict__ hw,
                         const int2* __restrict__ ovf, const int* __restrict__ ovf_cnt,
                         int n, int mode) {
    int node = blockIdx.x * 4 + (threadIdx.x >> 6);
    if (node >= n) return;
    int lane = threadIdx.x & 63;
    int g = lane >> 4, cl = lane & 15;
    const float4* h4 = (const float4*)h;
    float dc = dis[node];
    float4 hv = h4[node * 16 + cl];
    float4 S = (g == 0) ? make_float4(dc * hv.x, dc * hv.y, dc * hv.z, dc * hv.w)
                        : make_float4(0.f, 0.f, 0.f, 0.f);
    int degFull = cur[node];
    int deg = min(degFull, CAP);
    const int4* bp4 = (const int4*)(bucket + node * CAP);  // 160 B stride, 16B-aligned
    for (int base = g * 4; base < deg; base += 16) {
        int4 e = bp4[base >> 2];
        int r0 = (base + 0 < deg) ? e.x : node;
        int r1 = (base + 1 < deg) ? e.y : node;
        int r2 = (base + 2 < deg) ? e.z : node;
        int r3 = (base + 3 < deg) ? e.w : node;
        float w0 = (base + 0 < deg) ? dis[r0] : 0.f;
        float w1 = (base + 1 < deg) ? dis[r1] : 0.f;
        float w2 = (base + 2 < deg) ? dis[r2] : 0.f;
        float w3 = (base + 3 < deg) ? dis[r3] : 0.f;
        float4 v0 = h4[r0 * 16 + cl];
        float4 v1 = h4[r1 * 16 + cl];
        float4 v2 = h4[r2 * 16 + cl];
        float4 v3 = h4[r3 * 16 + cl];
        S.x += w0 * v0.x + w1 * v1.x + w2 * v2.x + w3 * v3.x;
        S.y += w0 * v0.y + w1 * v1.y + w2 * v2.y + w3 * v3.y;
        S.z += w0 * v0.z + w1 * v1.z + w2 * v2.z + w3 * v3.z;
        S.w += w0 * v0.w + w1 * v1.w + w2 * v2.w + w3 * v3.w;
    }
    if (degFull > CAP) {  // overflow: scan spill list for edges into this node
        int m = min(*ovf_cnt, OVF_CAP);
        for (int i = g; i < m; i += 4) {
            int2 p = ovf[i];
            if (p.y == node) {
                float w = dis[p.x];
                float4 v = h4[p.x * 16 + cl];
                S.x += w * v.x; S.y += w * v.y; S.z += w * v.z; S.w += w * v.w;
            }
        }
    }
    // reduce the 4 edge-groups (same cl): xor lanes 16, 32
    S.x += __shfl_xor(S.x, 16); S.y += __shfl_xor(S.y, 16);
    S.z += __shfl_xor(S.z, 16); S.w += __shfl_xor(S.w, 16);
    S.x += __shfl_xor(S.x, 32); S.y += __shfl_xor(S.y, 32);
    S.z += __shfl_xor(S.z, 32); S.w += __shfl_xor(S.w, 32);
    float4 acc = make_float4(dc * S.x, dc * S.y, dc * S.z, dc * S.w);
    if (mode == 2) {
        float w0 = hw[0], w1 = hw[1];
        acc.x = w0 * hv.x + w1 * acc.x;
        acc.y = w0 * hv.y + w1 * acc.y;
        acc.z = w0 * hv.z + w1 * acc.z;
        acc.w = w0 * hv.w + w1 * acc.w;
    }
    if (g == 0) ((float4*)out)[node * 16 + cl] = acc;
}

// ---- launch --------------------------------------------------------------

static inline size_t align_up(size_t v, size_t a) { return (v + a - 1) & ~(a - 1); }

extern "C" void kernel_launch(void* const* d_in, const int* in_sizes, int n_in,
                              void* d_out, int out_size, void* d_ws, size_t ws_size,
                              hipStream_t stream) {
    const float* x   = (const float*)d_in[0];
    const int*   ei  = (const int*)d_in[1];
    const float* W1  = (const float*)d_in[2];
    const float* b1  = (const float*)d_in[3];
    const float* hw1 = (const float*)d_in[4];
    const float* W2  = (const float*)d_in[5];
    const float* b2  = (const float*)d_in[6];
    const float* hw2 = (const float*)d_in[7];
    float* out = (float*)d_out;

    const int E = in_sizes[1] / 2;
    const int n = out_size / 64;
    const int* row = ei;
    const int* col = ei + E;

    char* ws = (char*)d_ws;
    size_t o = 0;
    float* dis    = (float*)(ws + o); o = align_up(o + (size_t)n * 4, 512);
    int*   cur    = (int*)(ws + o);   size_t z0 = o; o = align_up(o + (size_t)n * 4, 512);
    int*   deg    = (int*)(ws + o);   o = align_up(o + (size_t)n * 4, 512);
    int*   ovfcnt = (int*)(ws + o);   size_t z1 = o + 4; o = align_up(z1, 512);
    int*   bucket = (int*)(ws + o);   o = align_up(o + (size_t)n * CAP * 4, 512);
    int2*  ovf    = (int2*)(ws + o);  o = align_up(o + (size_t)OVF_CAP * 8, 512);
    float* A      = (float*)(ws + o); o += (size_t)n * 64 * 4;
    float* B      = (float*)(ws + o); o += (size_t)n * 64 * 4;
    (void)ws_size;

    const int nBuild = (E + TPB - 1) / TPB;
    const int nLin   = (n + 15) / 16;
    dim3 blk(TPB);
    dim3 gN((n + TPB - 1) / TPB);
    dim3 gG((n + 3) / 4);      // 1 wave per node, 4 waves per block
    dim3 gLin(nLin);

    // zero cur/deg/ovf_cnt, then fused {build | lin128}
    (void)hipMemsetAsync(ws + z0, 0, z1 - z0, stream);
    k_build_lin<<<dim3(nBuild + nLin), blk, 0, stream>>>(
        row, col, cur, deg, bucket, ovf, ovfcnt, E, nBuild,
        x, W1, b1, A, n);                                                   // A = h0
    k_dis<<<gN, blk, 0, stream>>>(deg, dis, n);

    // ---- layer 1 ----  (combine+relu deferred into k_lin64_relu2)
    k_gather<<<gG, blk, 0, stream>>>(A, B, cur, bucket, dis, hw1, ovf, ovfcnt, n, 0);   // B = h1
    k_gather<<<gG, blk, 0, stream>>>(B, out, cur, bucket, dis, hw1, ovf, ovfcnt, n, 0); // out = h2

    // ---- layer 2 ----
    k_lin64_relu2<<<gLin, blk, 0, stream>>>(B, out, W2, b2, hw1, A, n);                 // A = g0
    k_gather<<<gG, blk, 0, stream>>>(A, B, cur, bucket, dis, hw2, ovf, ovfcnt, n, 0);   // B = g1
    k_gather<<<gG, blk, 0, stream>>>(B, out, cur, bucket, dis, hw2, ovf, ovfcnt, n, 2); // out
}

// Round 9
// 303.899 us; speedup vs baseline: 11.7528x; 1.1557x over previous
//
#include <hip/hip_runtime.h>

// MultiHopGCN: x[N,128] f32, edge_index[2,E] i32, W1[128,64], b1[64], hw1[2],
//              W2[64,64], b2[64], hw2[2] -> out[N,64] f32
// Bucketed-CSC build fused with layer-1 GEMM (split-K, 24.8KB LDS, Bresenham
// block interleave). Wave-per-node gather computes rsqrt norms on the fly.

#define TPB 256
#define CAP 40
#define OVF_CAP 65536

// ---- fused build + lin128 -------------------------------------------------
// Build blocks and GEMM blocks interleaved via Bresenham mapping so both
// kinds are co-resident (build = atomic-latency-bound, GEMM = VALU-bound).
__global__ void k_build_lin(const int* __restrict__ row, const int* __restrict__ col,
                            int* __restrict__ cur, int* __restrict__ deg,
                            int* __restrict__ bucket, int2* __restrict__ ovf,
                            int* __restrict__ ovf_cnt, int E, int nBuild, int nTotal,
                            const float* __restrict__ x, const float* __restrict__ W,
                            const float* __restrict__ b, float* __restrict__ out, int n) {
    int bid = blockIdx.x;
    int b_lo = (int)(((long long)bid * nBuild) / nTotal);
    int b_hi = (int)(((long long)(bid + 1) * nBuild) / nTotal);
    if (b_hi > b_lo) {
        // ---- build path (block index b_lo) ----
        int i = b_lo * TPB + threadIdx.x;
        if (i >= E) return;
        int r = row[i], c = col[i];
        atomicAdd(&deg[r], 1);
        int slot = atomicAdd(&cur[c], 1);
        if (slot < CAP) {
            bucket[c * CAP + slot] = r;
        } else {
            int p = atomicAdd(ovf_cnt, 1);
            if (p < OVF_CAP) ovf[p] = make_int2(r, c);
        }
        return;
    }
    // ---- lin128 path (block index bid - b_lo), split-K: Ws is 64x64 ----
    __shared__ float Ws[64][64];
    __shared__ float xs[16][132];
    int tid = threadIdx.x;
    int row0 = (bid - b_lo) * 16;
    for (int i = tid; i < 16 * 32; i += TPB) {
        int r = i >> 5, k4 = i & 31;
        int gr = row0 + r;
        float4 v = (gr < n) ? ((const float4*)(x + (size_t)gr * 128))[k4]
                            : make_float4(0.f, 0.f, 0.f, 0.f);
        ((float4*)&xs[r][0])[k4] = v;
    }
    int r = tid >> 4, c4 = (tid & 15) * 4;
    float4 acc = make_float4(b[c4], b[c4 + 1], b[c4 + 2], b[c4 + 3]);
#pragma unroll
    for (int half = 0; half < 2; ++half) {
        for (int i = tid; i < 64 * 64 / 4; i += TPB)
            ((float4*)&Ws[0][0])[i] = ((const float4*)W)[half * 1024 + i];
        __syncthreads();
#pragma unroll 8
        for (int k = 0; k < 64; ++k) {
            float xv = xs[r][half * 64 + k];
            float4 w = *(const float4*)&Ws[k][c4];
            acc.x += xv * w.x;
            acc.y += xv * w.y;
            acc.z += xv * w.z;
            acc.w += xv * w.w;
        }
        __syncthreads();
    }
    int gr = row0 + r;
    if (gr < n) *(float4*)(out + (size_t)gr * 64 + c4) = acc;
}

// g0 = relu(hw[0]*hA + hw[1]*hB) @ W[64,64] + b   (combine fused into staging)
__global__ void k_lin64_relu2(const float* __restrict__ hA, const float* __restrict__ hB,
                              const float* __restrict__ W, const float* __restrict__ b,
                              const float* __restrict__ hw, float* __restrict__ out, int n) {
    __shared__ float Ws[64][64];
    __shared__ float xs[16][68];
    int tid = threadIdx.x;
    for (int i = tid; i < 64 * 64 / 4; i += TPB)
        ((float4*)&Ws[0][0])[i] = ((const float4*)W)[i];
    float w0 = hw[0], w1 = hw[1];
    int row0 = blockIdx.x * 16;
    for (int i = tid; i < 16 * 16; i += TPB) {
        int r = i >> 4, k4 = i & 15;
        int gr = row0 + r;
        float4 v = make_float4(0.f, 0.f, 0.f, 0.f);
        if (gr < n) {
            float4 a = ((const float4*)(hA + (size_t)gr * 64))[k4];
            float4 c = ((const float4*)(hB + (size_t)gr * 64))[k4];
            v.x = fmaxf(w0 * a.x + w1 * c.x, 0.f);
            v.y = fmaxf(w0 * a.y + w1 * c.y, 0.f);
            v.z = fmaxf(w0 * a.z + w1 * c.z, 0.f);
            v.w = fmaxf(w0 * a.w + w1 * c.w, 0.f);
        }
        ((float4*)&xs[r][0])[k4] = v;
    }
    __syncthreads();
    int r = tid >> 4, c4 = (tid & 15) * 4;
    float4 acc = make_float4(b[c4], b[c4 + 1], b[c4 + 2], b[c4 + 3]);
#pragma unroll 8
    for (int k = 0; k < 64; ++k) {
        float xv = xs[r][k];
        float4 w = *(const float4*)&Ws[k][c4];
        acc.x += xv * w.x;
        acc.y += xv * w.y;
        acc.z += xv * w.z;
        acc.w += xv * w.w;
    }
    int gr = row0 + r;
    if (gr < n) *(float4*)(out + (size_t)gr * 64 + c4) = acc;
}

// Wave-per-node gather: 4 edge-groups x 16 channel-lanes (float4).
// Norms computed on the fly: w(r) = rsqrt(deg[r]+1). Overflow handled inline.
//   agg = dc*(dc*h[c] + sum_e w(r)*h[r])
// mode 0: out = agg;  mode 2: out = hw[0]*h + hw[1]*agg
__global__ void k_gather(const float* __restrict__ h, float* __restrict__ out,
                         const int* __restrict__ cur, const int* __restrict__ bucket,
                         const int* __restrict__ deg_, const float* __restrict__ hw,
                         const int2* __restrict__ ovf, const int* __restrict__ ovf_cnt,
                         int n, int mode) {
    int node = blockIdx.x * 4 + (threadIdx.x >> 6);
    if (node >= n) return;
    int lane = threadIdx.x & 63;
    int g = lane >> 4, cl = lane & 15;
    const float4* h4 = (const float4*)h;
    float dc = rsqrtf((float)deg_[node] + 1.0f);
    float4 hv = h4[node * 16 + cl];
    float4 S = (g == 0) ? make_float4(dc * hv.x, dc * hv.y, dc * hv.z, dc * hv.w)
                        : make_float4(0.f, 0.f, 0.f, 0.f);
    int degFull = cur[node];
    int deg = min(degFull, CAP);
    const int4* bp4 = (const int4*)(bucket + node * CAP);  // 160 B stride, 16B-aligned
    for (int base = g * 4; base < deg; base += 16) {
        int4 e = bp4[base >> 2];
        int r0 = (base + 0 < deg) ? e.x : node;
        int r1 = (base + 1 < deg) ? e.y : node;
        int r2 = (base + 2 < deg) ? e.z : node;
        int r3 = (base + 3 < deg) ? e.w : node;
        int d0 = deg_[r0], d1 = deg_[r1], d2 = deg_[r2], d3 = deg_[r3];
        float w0 = (base + 0 < deg) ? rsqrtf((float)d0 + 1.f) : 0.f;
        float w1 = (base + 1 < deg) ? rsqrtf((float)d1 + 1.f) : 0.f;
        float w2 = (base + 2 < deg) ? rsqrtf((float)d2 + 1.f) : 0.f;
        float w3 = (base + 3 < deg) ? rsqrtf((float)d3 + 1.f) : 0.f;
        float4 v0 = h4[r0 * 16 + cl];
        float4 v1 = h4[r1 * 16 + cl];
        float4 v2 = h4[r2 * 16 + cl];
        float4 v3 = h4[r3 * 16 + cl];
        S.x += w0 * v0.x + w1 * v1.x + w2 * v2.x + w3 * v3.x;
        S.y += w0 * v0.y + w1 * v1.y + w2 * v2.y + w3 * v3.y;
        S.z += w0 * v0.z + w1 * v1.z + w2 * v2.z + w3 * v3.z;
        S.w += w0 * v0.w + w1 * v1.w + w2 * v2.w + w3 * v3.w;
    }
    if (degFull > CAP) {  // overflow: scan spill list for edges into this node
        int m = min(*ovf_cnt, OVF_CAP);
        for (int i = g; i < m; i += 4) {
            int2 p = ovf[i];
            if (p.y == node) {
                float w = rsqrtf((float)deg_[p.x] + 1.f);
                float4 v = h4[p.x * 16 + cl];
                S.x += w * v.x; S.y += w * v.y; S.z += w * v.z; S.w += w * v.w;
            }
        }
    }
    // reduce the 4 edge-groups (same cl): xor lanes 16, 32
    S.x += __shfl_xor(S.x, 16); S.y += __shfl_xor(S.y, 16);
    S.z += __shfl_xor(S.z, 16); S.w += __shfl_xor(S.w, 16);
    S.x += __shfl_xor(S.x, 32); S.y += __shfl_xor(S.y, 32);
    S.z += __shfl_xor(S.z, 32); S.w += __shfl_xor(S.w, 32);
    float4 acc = make_float4(dc * S.x, dc * S.y, dc * S.z, dc * S.w);
    if (mode == 2) {
        float w0 = hw[0], w1 = hw[1];
        acc.x = w0 * hv.x + w1 * acc.x;
        acc.y = w0 * hv.y + w1 * acc.y;
        acc.z = w0 * hv.z + w1 * acc.z;
        acc.w = w0 * hv.w + w1 * acc.w;
    }
    if (g == 0) ((float4*)out)[node * 16 + cl] = acc;
}

// ---- launch --------------------------------------------------------------

static inline size_t align_up(size_t v, size_t a) { return (v + a - 1) & ~(a - 1); }

extern "C" void kernel_launch(void* const* d_in, const int* in_sizes, int n_in,
                              void* d_out, int out_size, void* d_ws, size_t ws_size,
                              hipStream_t stream) {
    const float* x   = (const float*)d_in[0];
    const int*   ei  = (const int*)d_in[1];
    const float* W1  = (const float*)d_in[2];
    const float* b1  = (const float*)d_in[3];
    const float* hw1 = (const float*)d_in[4];
    const float* W2  = (const float*)d_in[5];
    const float* b2  = (const float*)d_in[6];
    const float* hw2 = (const float*)d_in[7];
    float* out = (float*)d_out;

    const int E = in_sizes[1] / 2;
    const int n = out_size / 64;
    const int* row = ei;
    const int* col = ei + E;

    char* ws = (char*)d_ws;
    size_t o = 0;
    int*   cur    = (int*)(ws + o);   size_t z0 = o; o = align_up(o + (size_t)n * 4, 512);
    int*   deg    = (int*)(ws + o);   o = align_up(o + (size_t)n * 4, 512);
    int*   ovfcnt = (int*)(ws + o);   size_t z1 = o + 4; o = align_up(z1, 512);
    int*   bucket = (int*)(ws + o);   o = align_up(o + (size_t)n * CAP * 4, 512);
    int2*  ovf    = (int2*)(ws + o);  o = align_up(o + (size_t)OVF_CAP * 8, 512);
    float* A      = (float*)(ws + o); o += (size_t)n * 64 * 4;
    float* B      = (float*)(ws + o); o += (size_t)n * 64 * 4;
    (void)ws_size;

    const int nBuild = (E + TPB - 1) / TPB;
    const int nLin   = (n + 15) / 16;
    const int nTotal = nBuild + nLin;
    dim3 blk(TPB);
    dim3 gG((n + 3) / 4);      // 1 wave per node, 4 waves per block
    dim3 gLin(nLin);

    // zero cur/deg/ovf_cnt, then fused {build | lin128} (interleaved blocks)
    (void)hipMemsetAsync(ws + z0, 0, z1 - z0, stream);
    k_build_lin<<<dim3(nTotal), blk, 0, stream>>>(
        row, col, cur, deg, bucket, ovf, ovfcnt, E, nBuild, nTotal,
        x, W1, b1, A, n);                                                   // A = h0

    // ---- layer 1 ----  (combine+relu deferred into k_lin64_relu2)
    k_gather<<<gG, blk, 0, stream>>>(A, B, cur, bucket, deg, hw1, ovf, ovfcnt, n, 0);   // B = h1
    k_gather<<<gG, blk, 0, stream>>>(B, out, cur, bucket, deg, hw1, ovf, ovfcnt, n, 0); // out = h2

    // ---- layer 2 ----
    k_lin64_relu2<<<gLin, blk, 0, stream>>>(B, out, W2, b2, hw1, A, n);                 // A = g0
    k_gather<<<gG, blk, 0, stream>>>(A, B, cur, bucket, deg, hw2, ovf, ovfcnt, n, 0);   // B = g1
    k_gather<<<gG, blk, 0, stream>>>(B, out, cur, bucket, deg, hw2, ovf, ovfcnt, n, 2); // out
}

// Round 10
// 278.004 us; speedup vs baseline: 12.8475x; 1.0931x over previous
//
#include <hip/hip_runtime.h>

// MultiHopGCN: x[N,128] f32, edge_index[2,E] i32, W1[128,64], b1[64], hw1[2],
//              W2[64,64], b2[64], hw2[2] -> out[N,64] f32
// Bucketed-CSC build fused with layer-1 GEMM; wave-per-node gather.
// Intermediate feature buffers in bf16 (halves gather row-fetch traffic);
// all accumulation in f32; final output f32.

#define TPB 256
#define CAP 40
#define OVF_CAP 65536

// bf16 helpers (RNE)
__device__ __forceinline__ ushort f2b(float f) {
    union { float f; unsigned u; } v; v.f = f;
    unsigned r = v.u + 0x7FFFu + ((v.u >> 16) & 1u);
    return (ushort)(r >> 16);
}
__device__ __forceinline__ float b2f(ushort b) {
    union { unsigned u; float f; } v; v.u = ((unsigned)b) << 16;
    return v.f;
}
__device__ __forceinline__ float4 b4f(ushort4 b) {
    return make_float4(b2f(b.x), b2f(b.y), b2f(b.z), b2f(b.w));
}
__device__ __forceinline__ ushort4 f4b(float4 f) {
    ushort4 r; r.x = f2b(f.x); r.y = f2b(f.y); r.z = f2b(f.z); r.w = f2b(f.w);
    return r;
}

// ---- fused build + lin128 -------------------------------------------------
// Build blocks and GEMM blocks Bresenham-interleaved so both kinds co-reside.
__global__ void k_build_lin(const int* __restrict__ row, const int* __restrict__ col,
                            int* __restrict__ cur, int* __restrict__ deg,
                            int* __restrict__ bucket, int2* __restrict__ ovf,
                            int* __restrict__ ovf_cnt, int E, int nBuild, int nTotal,
                            const float* __restrict__ x, const float* __restrict__ W,
                            const float* __restrict__ b, ushort4* __restrict__ outb, int n) {
    int bid = blockIdx.x;
    int b_lo = (int)(((long long)bid * nBuild) / nTotal);
    int b_hi = (int)(((long long)(bid + 1) * nBuild) / nTotal);
    if (b_hi > b_lo) {
        // ---- build path ----
        int i = b_lo * TPB + threadIdx.x;
        if (i >= E) return;
        int r = row[i], c = col[i];
        atomicAdd(&deg[r], 1);
        int slot = atomicAdd(&cur[c], 1);
        if (slot < CAP) {
            bucket[c * CAP + slot] = r;
        } else {
            int p = atomicAdd(ovf_cnt, 1);
            if (p < OVF_CAP) ovf[p] = make_int2(r, c);
        }
        return;
    }
    // ---- lin128 path (split-K: Ws is 64x64) ----
    __shared__ float Ws[64][64];
    __shared__ float xs[16][132];
    int tid = threadIdx.x;
    int row0 = (bid - b_lo) * 16;
    for (int i = tid; i < 16 * 32; i += TPB) {
        int r = i >> 5, k4 = i & 31;
        int gr = row0 + r;
        float4 v = (gr < n) ? ((const float4*)(x + (size_t)gr * 128))[k4]
                            : make_float4(0.f, 0.f, 0.f, 0.f);
        ((float4*)&xs[r][0])[k4] = v;
    }
    int r = tid >> 4, c4 = (tid & 15) * 4;
    float4 acc = make_float4(b[c4], b[c4 + 1], b[c4 + 2], b[c4 + 3]);
#pragma unroll
    for (int half = 0; half < 2; ++half) {
        for (int i = tid; i < 64 * 64 / 4; i += TPB)
            ((float4*)&Ws[0][0])[i] = ((const float4*)W)[half * 1024 + i];
        __syncthreads();
#pragma unroll 8
        for (int k = 0; k < 64; ++k) {
            float xv = xs[r][half * 64 + k];
            float4 w = *(const float4*)&Ws[k][c4];
            acc.x += xv * w.x;
            acc.y += xv * w.y;
            acc.z += xv * w.z;
            acc.w += xv * w.w;
        }
        __syncthreads();
    }
    int gr = row0 + r;
    if (gr < n) outb[(size_t)gr * 16 + (tid & 15)] = f4b(acc);
}

// g0 = relu(hw[0]*hA + hw[1]*hB) @ W[64,64] + b   (bf16 in, bf16 out)
__global__ void k_lin64_relu2(const ushort4* __restrict__ hA, const ushort4* __restrict__ hB,
                              const float* __restrict__ W, const float* __restrict__ b,
                              const float* __restrict__ hw, ushort4* __restrict__ outb, int n) {
    __shared__ float Ws[64][64];
    __shared__ float xs[16][68];
    int tid = threadIdx.x;
    for (int i = tid; i < 64 * 64 / 4; i += TPB)
        ((float4*)&Ws[0][0])[i] = ((const float4*)W)[i];
    float w0 = hw[0], w1 = hw[1];
    int row0 = blockIdx.x * 16;
    for (int i = tid; i < 16 * 16; i += TPB) {
        int r = i >> 4, k4 = i & 15;
        int gr = row0 + r;
        float4 v = make_float4(0.f, 0.f, 0.f, 0.f);
        if (gr < n) {
            float4 a = b4f(hA[(size_t)gr * 16 + k4]);
            float4 c = b4f(hB[(size_t)gr * 16 + k4]);
            v.x = fmaxf(w0 * a.x + w1 * c.x, 0.f);
            v.y = fmaxf(w0 * a.y + w1 * c.y, 0.f);
            v.z = fmaxf(w0 * a.z + w1 * c.z, 0.f);
            v.w = fmaxf(w0 * a.w + w1 * c.w, 0.f);
        }
        ((float4*)&xs[r][0])[k4] = v;
    }
    __syncthreads();
    int r = tid >> 4, c4 = (tid & 15) * 4;
    float4 acc = make_float4(b[c4], b[c4 + 1], b[c4 + 2], b[c4 + 3]);
#pragma unroll 8
    for (int k = 0; k < 64; ++k) {
        float xv = xs[r][k];
        float4 w = *(const float4*)&Ws[k][c4];
        acc.x += xv * w.x;
        acc.y += xv * w.y;
        acc.z += xv * w.z;
        acc.w += xv * w.w;
    }
    int gr = row0 + r;
    if (gr < n) outb[(size_t)gr * 16 + (tid & 15)] = f4b(acc);
}

// Wave-per-node gather: 4 edge-groups x 16 channel-lanes (4 bf16 ch/lane).
// Norms on the fly: w(r) = rsqrt(deg[r]+1). Overflow handled inline.
//   agg = dc*(dc*h[c] + sum_e w(r)*h[r])
// mode 0: outb = bf16(agg);  mode 2: outf = hw[0]*h + hw[1]*agg  (f32)
__global__ void k_gather(const ushort4* __restrict__ h, ushort4* __restrict__ outb,
                         float4* __restrict__ outf,
                         const int* __restrict__ cur, const int* __restrict__ bucket,
                         const int* __restrict__ deg_, const float* __restrict__ hw,
                         const int2* __restrict__ ovf, const int* __restrict__ ovf_cnt,
                         int n, int mode) {
    int node = blockIdx.x * 4 + (threadIdx.x >> 6);
    if (node >= n) return;
    int lane = threadIdx.x & 63;
    int g = lane >> 4, cl = lane & 15;
    float dc = rsqrtf((float)deg_[node] + 1.0f);
    float4 hv = b4f(h[(size_t)node * 16 + cl]);
    float4 S = (g == 0) ? make_float4(dc * hv.x, dc * hv.y, dc * hv.z, dc * hv.w)
                        : make_float4(0.f, 0.f, 0.f, 0.f);
    int degFull = cur[node];
    int deg = min(degFull, CAP);
    const int4* bp4 = (const int4*)(bucket + node * CAP);  // 160 B stride
    for (int base = g * 4; base < deg; base += 16) {
        int4 e = bp4[base >> 2];
        int r0 = (base + 0 < deg) ? e.x : node;
        int r1 = (base + 1 < deg) ? e.y : node;
        int r2 = (base + 2 < deg) ? e.z : node;
        int r3 = (base + 3 < deg) ? e.w : node;
        int d0 = deg_[r0], d1 = deg_[r1], d2 = deg_[r2], d3 = deg_[r3];
        float w0 = (base + 0 < deg) ? rsqrtf((float)d0 + 1.f) : 0.f;
        float w1 = (base + 1 < deg) ? rsqrtf((float)d1 + 1.f) : 0.f;
        float w2 = (base + 2 < deg) ? rsqrtf((float)d2 + 1.f) : 0.f;
        float w3 = (base + 3 < deg) ? rsqrtf((float)d3 + 1.f) : 0.f;
        float4 v0 = b4f(h[(size_t)r0 * 16 + cl]);
        float4 v1 = b4f(h[(size_t)r1 * 16 + cl]);
        float4 v2 = b4f(h[(size_t)r2 * 16 + cl]);
        float4 v3 = b4f(h[(size_t)r3 * 16 + cl]);
        S.x += w0 * v0.x + w1 * v1.x + w2 * v2.x + w3 * v3.x;
        S.y += w0 * v0.y + w1 * v1.y + w2 * v2.y + w3 * v3.y;
        S.z += w0 * v0.z + w1 * v1.z + w2 * v2.z + w3 * v3.z;
        S.w += w0 * v0.w + w1 * v1.w + w2 * v2.w + w3 * v3.w;
    }
    if (degFull > CAP) {  // overflow: scan spill list for edges into this node
        int m = min(*ovf_cnt, OVF_CAP);
        for (int i = g; i < m; i += 4) {
            int2 p = ovf[i];
            if (p.y == node) {
                float w = rsqrtf((float)deg_[p.x] + 1.f);
                float4 v = b4f(h[(size_t)p.x * 16 + cl]);
                S.x += w * v.x; S.y += w * v.y; S.z += w * v.z; S.w += w * v.w;
            }
        }
    }
    // reduce the 4 edge-groups (same cl): xor lanes 16, 32
    S.x += __shfl_xor(S.x, 16); S.y += __shfl_xor(S.y, 16);
    S.z += __shfl_xor(S.z, 16); S.w += __shfl_xor(S.w, 16);
    S.x += __shfl_xor(S.x, 32); S.y += __shfl_xor(S.y, 32);
    S.z += __shfl_xor(S.z, 32); S.w += __shfl_xor(S.w, 32);
    if (g != 0) return;
    float4 acc = make_float4(dc * S.x, dc * S.y, dc * S.z, dc * S.w);
    if (mode == 2) {
        float w0 = hw[0], w1 = hw[1];
        acc.x = w0 * hv.x + w1 * acc.x;
        acc.y = w0 * hv.y + w1 * acc.y;
        acc.z = w0 * hv.z + w1 * acc.z;
        acc.w = w0 * hv.w + w1 * acc.w;
        outf[(size_t)node * 16 + cl] = acc;
    } else {
        outb[(size_t)node * 16 + cl] = f4b(acc);
    }
}

// ---- launch --------------------------------------------------------------

static inline size_t align_up(size_t v, size_t a) { return (v + a - 1) & ~(a - 1); }

extern "C" void kernel_launch(void* const* d_in, const int* in_sizes, int n_in,
                              void* d_out, int out_size, void* d_ws, size_t ws_size,
                              hipStream_t stream) {
    const float* x   = (const float*)d_in[0];
    const int*   ei  = (const int*)d_in[1];
    const float* W1  = (const float*)d_in[2];
    const float* b1  = (const float*)d_in[3];
    const float* hw1 = (const float*)d_in[4];
    const float* W2  = (const float*)d_in[5];
    const float* b2  = (const float*)d_in[6];
    const float* hw2 = (const float*)d_in[7];
    float* out = (float*)d_out;

    const int E = in_sizes[1] / 2;
    const int n = out_size / 64;
    const int* row = ei;
    const int* col = ei + E;

    char* ws = (char*)d_ws;
    size_t o = 0;
    int*     cur    = (int*)(ws + o);     size_t z0 = o; o = align_up(o + (size_t)n * 4, 512);
    int*     deg    = (int*)(ws + o);     o = align_up(o + (size_t)n * 4, 512);
    int*     ovfcnt = (int*)(ws + o);     size_t z1 = o + 4; o = align_up(z1, 512);
    int*     bucket = (int*)(ws + o);     o = align_up(o + (size_t)n * CAP * 4, 512);
    int2*    ovf    = (int2*)(ws + o);    o = align_up(o + (size_t)OVF_CAP * 8, 512);
    ushort4* A      = (ushort4*)(ws + o); o = align_up(o + (size_t)n * 64 * 2, 512);
    ushort4* B      = (ushort4*)(ws + o); o = align_up(o + (size_t)n * 64 * 2, 512);
    ushort4* C      = (ushort4*)(ws + o); o = align_up(o + (size_t)n * 64 * 2, 512);
    (void)ws_size;

    const int nBuild = (E + TPB - 1) / TPB;
    const int nLin   = (n + 15) / 16;
    const int nTotal = nBuild + nLin;
    dim3 blk(TPB);
    dim3 gG((n + 3) / 4);      // 1 wave per node, 4 waves per block
    dim3 gLin(nLin);

    // zero cur/deg/ovf_cnt, then fused {build | lin128} (interleaved blocks)
    (void)hipMemsetAsync(ws + z0, 0, z1 - z0, stream);
    k_build_lin<<<dim3(nTotal), blk, 0, stream>>>(
        row, col, cur, deg, bucket, ovf, ovfcnt, E, nBuild, nTotal,
        x, W1, b1, A, n);                                                   // A = h0 (bf16)

    // ---- layer 1 ----  (combine+relu fused into k_lin64_relu2 staging)
    k_gather<<<gG, blk, 0, stream>>>(A, B, nullptr, cur, bucket, deg, hw1,
                                     ovf, ovfcnt, n, 0);                    // B = h1
    k_gather<<<gG, blk, 0, stream>>>(B, C, nullptr, cur, bucket, deg, hw1,
                                     ovf, ovfcnt, n, 0);                    // C = h2

    // ---- layer 2 ----
    k_lin64_relu2<<<gLin, blk, 0, stream>>>(B, C, W2, b2, hw1, A, n);       // A = g0
    k_gather<<<gG, blk, 0, stream>>>(A, B, nullptr, cur, bucket, deg, hw2,
                                     ovf, ovfcnt, n, 0);                    // B = g1
    k_gather<<<gG, blk, 0, stream>>>(B, nullptr, (float4*)out, cur, bucket, deg, hw2,
                                     ovf, ovfcnt, n, 2);                    // out = w0*g1+w1*agg
}